// Round 1
// baseline (7412.753 us; speedup 1.0000x reference)
//
#include <hip/hip_runtime.h>
#include <hip/hip_bf16.h>

#define HF 128  // feature/hidden dim (F == H == 128)

// ---------------- scatter-add: agg[dst] += x[src], edge-parallel ----------------
// 32 threads per edge, each handles a float4 chunk (4 atomics).
__global__ __launch_bounds__(256) void scatter_add(
    const float* __restrict__ xin, const int* __restrict__ src,
    const int* __restrict__ dst, float* __restrict__ agg, int E)
{
    int idx = blockIdx.x * 256 + threadIdx.x;
    if (idx >= E * 32) return;
    int e = idx >> 5;
    int c = (idx & 31) << 2;
    int s = src[e], d = dst[e];
    float4 v = *(const float4*)(xin + (size_t)s * HF + c);
    float* o = agg + (size_t)d * HF + c;
    atomicAdd(o + 0, v.x);
    atomicAdd(o + 1, v.y);
    atomicAdd(o + 2, v.z);
    atomicAdd(o + 3, v.w);
}

// ---------------- GEMM: out = relu(U @ W + b), U = (1+eps)*X + AGG (optional fuse)
// Block: 256 threads, 32 rows per block, full 128 cols, K=128.
// Thread (colg=tid&31, rowg=tid>>5) computes a 4x4 register tile.
template <bool FUSE_IN>
__global__ __launch_bounds__(256) void gemm_relu(
    const float* __restrict__ X, const float* __restrict__ AGG,
    const float* __restrict__ epsp,
    const float* __restrict__ W, const float* __restrict__ bias,
    float* __restrict__ out, int n)
{
    __shared__ float u[32][HF];
    int row0 = blockIdx.x * 32;
    int tid = threadIdx.x;
    float epsv = FUSE_IN ? (1.0f + epsp[0]) : 0.0f;

    // stage 32x128 input tile (fused (1+eps)*x + agg)
    for (int s = tid; s < 1024; s += 256) {
        int r = s >> 5;
        int c4 = (s & 31) << 2;
        int row = row0 + r;
        float4 v;
        if (row < n) {
            v = *(const float4*)(X + (size_t)row * HF + c4);
            if (FUSE_IN) {
                float4 a = *(const float4*)(AGG + (size_t)row * HF + c4);
                v.x = epsv * v.x + a.x;
                v.y = epsv * v.y + a.y;
                v.z = epsv * v.z + a.z;
                v.w = epsv * v.w + a.w;
            }
        } else {
            v = make_float4(0.f, 0.f, 0.f, 0.f);
        }
        *(float4*)(&u[r][c4]) = v;
    }
    __syncthreads();

    int col0 = (tid & 31) << 2;
    int r0 = (tid >> 5) << 2;
    float acc[4][4] = {};
#pragma unroll 4
    for (int k = 0; k < HF; k += 4) {
        float4 w0 = *(const float4*)(W + (size_t)(k + 0) * HF + col0);
        float4 w1 = *(const float4*)(W + (size_t)(k + 1) * HF + col0);
        float4 w2 = *(const float4*)(W + (size_t)(k + 2) * HF + col0);
        float4 w3 = *(const float4*)(W + (size_t)(k + 3) * HF + col0);
#pragma unroll
        for (int i = 0; i < 4; i++) {
            float4 uv = *(const float4*)(&u[r0 + i][k]);
            acc[i][0] += uv.x * w0.x + uv.y * w1.x + uv.z * w2.x + uv.w * w3.x;
            acc[i][1] += uv.x * w0.y + uv.y * w1.y + uv.z * w2.y + uv.w * w3.y;
            acc[i][2] += uv.x * w0.z + uv.y * w1.z + uv.z * w2.z + uv.w * w3.z;
            acc[i][3] += uv.x * w0.w + uv.y * w1.w + uv.z * w2.w + uv.w * w3.w;
        }
    }
    float4 bv = *(const float4*)(bias + col0);
#pragma unroll
    for (int i = 0; i < 4; i++) {
        int row = row0 + r0 + i;
        if (row < n) {
            float4 o;
            o.x = fmaxf(acc[i][0] + bv.x, 0.f);
            o.y = fmaxf(acc[i][1] + bv.y, 0.f);
            o.z = fmaxf(acc[i][2] + bv.z, 0.f);
            o.w = fmaxf(acc[i][3] + bv.w, 0.f);
            *(float4*)(out + (size_t)row * HF + col0) = o;
        }
    }
}

// ---------------- BN column stats: S1[c] += sum(h[:,c]), S2[c] += sum(h[:,c]^2)
__global__ void bn_stats(const float* __restrict__ h, float* __restrict__ S1,
                         float* __restrict__ S2, int n)
{
    int col = threadIdx.x;  // 128 threads
    float s = 0.f, q = 0.f;
    for (int r = blockIdx.x; r < n; r += gridDim.x) {
        float v = h[(size_t)r * HF + col];
        s += v;
        q += v * v;
    }
    atomicAdd(&S1[col], s);
    atomicAdd(&S2[col], q);
}

__global__ void bn_finalize(const float* __restrict__ S1, const float* __restrict__ S2,
                            const float* __restrict__ gamma, const float* __restrict__ beta,
                            float* __restrict__ scale, float* __restrict__ shift, float invN)
{
    int c = threadIdx.x;  // 128
    float mu = S1[c] * invN;
    float var = S2[c] * invN - mu * mu;
    float rs = rsqrtf(var + 1e-5f);
    float sc = gamma[c] * rs;
    scale[c] = sc;
    shift[c] = beta[c] - mu * sc;
}

__global__ __launch_bounds__(256) void bn_apply(
    const float* __restrict__ in, const float* __restrict__ scale,
    const float* __restrict__ shift, float* __restrict__ out, int total4)
{
    int i = blockIdx.x * 256 + threadIdx.x;
    if (i >= total4) return;
    int c4 = (i & 31) << 2;
    float4 v = ((const float4*)in)[i];
    float4 sc = *(const float4*)(scale + c4);
    float4 sh = *(const float4*)(shift + c4);
    v.x = v.x * sc.x + sh.x;
    v.y = v.y * sc.y + sh.y;
    v.z = v.z * sc.z + sh.z;
    v.w = v.w * sc.w + sh.w;
    ((float4*)out)[i] = v;
}

// ---------------- layer-2 tail: BN apply + pool atomics + mse, fused per node
// 256 threads = 4 nodes x 64 lanes; lane handles features f and f+64.
__global__ __launch_bounds__(256) void finalize_nodes(
    const float* __restrict__ t4, const float* __restrict__ scale,
    const float* __restrict__ shift, const int* __restrict__ batch,
    const float* __restrict__ degree, const float* __restrict__ Wloss,
    const float* __restrict__ blossp, float* __restrict__ sums,
    float* __restrict__ cnt, float* __restrict__ mse_acc, int n)
{
    int lane = threadIdx.x & 63;
    int wv = threadIdx.x >> 6;
    int node = blockIdx.x * 4 + wv;
    if (node >= n) return;
    int b = batch[node];
    const float* row = t4 + (size_t)node * HF;
    float m = 0.f;
#pragma unroll
    for (int h = 0; h < 2; h++) {
        int f = lane + h * 64;
        float v = row[f] * scale[f] + shift[f];
        atomicAdd(&sums[(size_t)b * HF + f], v);
        m += v * Wloss[f];
    }
#pragma unroll
    for (int off = 32; off > 0; off >>= 1) m += __shfl_down(m, off);
    if (lane == 0) {
        float d = m + blossp[0] - degree[node];
        atomicAdd(mse_acc, d * d);
        atomicAdd(cnt + b, 1.0f);
    }
}

// ---------------- pool divide + z = relu(g @ Wlin1 + blin1)
__global__ void pool_lin1(const float* __restrict__ sums, const float* __restrict__ cnt,
                          const float* __restrict__ W, const float* __restrict__ bias,
                          float* __restrict__ z)
{
    __shared__ float gv[HF];
    int gid = blockIdx.x;
    int c = threadIdx.x;  // 128
    float inv = 1.0f / fmaxf(cnt[gid], 1.0f);
    gv[c] = sums[(size_t)gid * HF + c] * inv;
    __syncthreads();
    float a = bias[c];
#pragma unroll 8
    for (int k = 0; k < HF; k++) a += gv[k] * W[(size_t)k * HF + c];
    z[(size_t)gid * HF + c] = fmaxf(a, 0.f);
}

// ---------------- heads: result1 = log_softmax(z@W2+b2), result3 = z@W4+b4
__global__ void heads(const float* __restrict__ z, const float* __restrict__ W2,
                      const float* __restrict__ b2, const float* __restrict__ W4,
                      const float* __restrict__ b4, float* __restrict__ out1,
                      float* __restrict__ out3, int C_, int D_)
{
    __shared__ float zr[HF];
    __shared__ float logits[16];
    __shared__ float lse_s;
    int gid = blockIdx.x;
    int t = threadIdx.x;  // 64
    zr[t] = z[(size_t)gid * HF + t];
    zr[t + 64] = z[(size_t)gid * HF + t + 64];
    __syncthreads();
    if (t < C_) {
        float a = b2[t];
        for (int k = 0; k < HF; k++) a += zr[k] * W2[(size_t)k * C_ + t];
        logits[t] = a;
    }
    __syncthreads();
    if (t == 0) {
        float mx = -1e30f;
        for (int i = 0; i < C_; i++) mx = fmaxf(mx, logits[i]);
        float s = 0.f;
        for (int i = 0; i < C_; i++) s += expf(logits[i] - mx);
        lse_s = mx + logf(s);
    }
    __syncthreads();
    if (t < C_) out1[(size_t)gid * C_ + t] = logits[t] - lse_s;
    if (t < D_) {
        float a = b4[t];
        for (int k = 0; k < HF; k++) a += zr[k] * W4[(size_t)k * D_ + t];
        out3[(size_t)gid * D_ + t] = a;
    }
}

__global__ void mse_final(const float* __restrict__ acc, float* __restrict__ out, float invN)
{
    out[0] = acc[0] * invN;
}

extern "C" void kernel_launch(void* const* d_in, const int* in_sizes, int n_in,
                              void* d_out, int out_size, void* d_ws, size_t ws_size,
                              hipStream_t stream)
{
    const float* x      = (const float*)d_in[0];
    const int*   ei     = (const int*)d_in[1];
    const int*   batch  = (const int*)d_in[2];
    const float* degree = (const float*)d_in[3];
    const float* eps1   = (const float*)d_in[4];
    const float* W1a    = (const float*)d_in[5];
    const float* b1a    = (const float*)d_in[6];
    const float* W1b    = (const float*)d_in[7];
    const float* b1b    = (const float*)d_in[8];
    const float* g1     = (const float*)d_in[9];
    const float* be1    = (const float*)d_in[10];
    const float* eps2   = (const float*)d_in[11];
    const float* W2a    = (const float*)d_in[12];
    const float* b2a    = (const float*)d_in[13];
    const float* W2b    = (const float*)d_in[14];
    const float* b2b    = (const float*)d_in[15];
    const float* g2     = (const float*)d_in[16];
    const float* be2    = (const float*)d_in[17];
    const float* Wlin1  = (const float*)d_in[18];
    const float* blin1  = (const float*)d_in[19];
    const float* Wlin2  = (const float*)d_in[20];
    const float* blin2  = (const float*)d_in[21];
    const float* Wlin4  = (const float*)d_in[22];
    const float* blin4  = (const float*)d_in[23];
    const float* Wloss  = (const float*)d_in[24];
    const float* bloss  = (const float*)d_in[25];

    const int N  = in_sizes[0] / HF;
    const int E  = in_sizes[1] / 2;
    const int C_ = in_sizes[21];
    const int D_ = in_sizes[23];
    const int Gn = (out_size - 1) / (C_ + D_);

    const int* src = ei;
    const int* dst = ei + E;

    float* ws = (float*)d_ws;
    size_t NH = (size_t)N * HF;
    float* A  = ws;            // agg (L1), then agg2 -> t4 (L2)
    float* B  = A + NH;        // t1, then t3
    float* Cb = B + NH;        // t2 -> h1 (in place)
    float* S1 = Cb + NH;
    float* S2 = S1 + HF;
    float* scale = S2 + HF;
    float* shift = scale + HF;
    float* sums  = shift + HF;
    float* cnt   = sums + (size_t)Gn * HF;
    float* macc  = cnt + Gn;
    float* z     = macc + 1;

    float* out1 = (float*)d_out;
    float* out3 = out1 + (size_t)Gn * C_;
    float* outm = out3 + (size_t)Gn * D_;

    int scBlocks   = (E * 32 + 255) / 256;
    int gemmBlocks = (N + 31) / 32;
    float invN = 1.0f / (float)N;

    // ---- layer 1 ----
    hipMemsetAsync(A, 0, NH * sizeof(float), stream);
    scatter_add<<<scBlocks, 256, 0, stream>>>(x, src, dst, A, E);
    gemm_relu<true><<<gemmBlocks, 256, 0, stream>>>(x, A, eps1, W1a, b1a, B, N);
    gemm_relu<false><<<gemmBlocks, 256, 0, stream>>>(B, nullptr, nullptr, W1b, b1b, Cb, N);
    hipMemsetAsync(S1, 0, 2 * HF * sizeof(float), stream);
    bn_stats<<<512, 128, 0, stream>>>(Cb, S1, S2, N);
    bn_finalize<<<1, 128, 0, stream>>>(S1, S2, g1, be1, scale, shift, invN);
    bn_apply<<<(N * 32 + 255) / 256, 256, 0, stream>>>(Cb, scale, shift, Cb, N * 32);

    // ---- layer 2 ----
    hipMemsetAsync(A, 0, NH * sizeof(float), stream);
    scatter_add<<<scBlocks, 256, 0, stream>>>(Cb, src, dst, A, E);
    gemm_relu<true><<<gemmBlocks, 256, 0, stream>>>(Cb, A, eps2, W2a, b2a, B, N);
    gemm_relu<false><<<gemmBlocks, 256, 0, stream>>>(B, nullptr, nullptr, W2b, b2b, A, N);
    hipMemsetAsync(S1, 0, 2 * HF * sizeof(float), stream);
    bn_stats<<<512, 128, 0, stream>>>(A, S1, S2, N);
    bn_finalize<<<1, 128, 0, stream>>>(S1, S2, g2, be2, scale, shift, invN);

    // ---- tail: BN2 apply + pool atomics + mse, then tiny dense heads ----
    hipMemsetAsync(sums, 0, ((size_t)Gn * HF + Gn + 1) * sizeof(float), stream);
    finalize_nodes<<<(N + 3) / 4, 256, 0, stream>>>(A, scale, shift, batch, degree,
                                                    Wloss, bloss, sums, cnt, macc, N);
    pool_lin1<<<Gn, 128, 0, stream>>>(sums, cnt, Wlin1, blin1, z);
    heads<<<Gn, 64, 0, stream>>>(z, Wlin2, blin2, Wlin4, blin4, out1, out3, C_, D_);
    mse_final<<<1, 1, 0, stream>>>(macc, outm, invN);
}

// Round 2
// 2498.919 us; speedup vs baseline: 2.9664x; 2.9664x over previous
//
#include <hip/hip_runtime.h>
#include <hip/hip_bf16.h>

#define HF 128  // feature/hidden dim (F == H == 128)

// ================= CSR build =================
__global__ __launch_bounds__(256) void deg_count(
    const int* __restrict__ dst, int* __restrict__ deg, int E)
{
    int e = blockIdx.x * 256 + threadIdx.x;
    if (e < E) atomicAdd(&deg[dst[e]], 1);
}

// block sums over chunks of 1024
__global__ __launch_bounds__(256) void scan_block_sums(
    const int* __restrict__ deg, int* __restrict__ bsum, int N)
{
    __shared__ int sdata[256];
    int b = blockIdx.x, t = threadIdx.x;
    int base = b * 1024;
    int s = 0;
    for (int i = t; i < 1024; i += 256) {
        int idx = base + i;
        s += (idx < N) ? deg[idx] : 0;
    }
    sdata[t] = s;
    __syncthreads();
    for (int off = 128; off > 0; off >>= 1) {
        if (t < off) sdata[t] += sdata[t + off];
        __syncthreads();
    }
    if (t == 0) bsum[b] = sdata[0];
}

// serial exclusive scan of block sums (nb ~ 98), writes off[N] = total
__global__ void scan_bsum(int* __restrict__ bsum, int nb, int* __restrict__ off, int N)
{
    if (threadIdx.x == 0) {
        int acc = 0;
        for (int i = 0; i < nb; i++) {
            int v = bsum[i];
            bsum[i] = acc;
            acc += v;
        }
        off[N] = acc;
    }
}

// final exclusive offsets + cursor init (cursor aliases deg: read-then-write per index)
__global__ __launch_bounds__(256) void scan_final(
    const int* __restrict__ deg, const int* __restrict__ bsum,
    int* __restrict__ off, int* __restrict__ cursor, int N)
{
    __shared__ int sd[256];
    int b = blockIdx.x, t = threadIdx.x;
    int base = b * 1024;
    int v[4];
    int loc = 0;
#pragma unroll
    for (int i = 0; i < 4; i++) {
        int idx = base + t * 4 + i;
        v[i] = (idx < N) ? deg[idx] : 0;
        loc += v[i];
    }
    sd[t] = loc;
    __syncthreads();
    for (int o = 1; o < 256; o <<= 1) {
        int xv = (t >= o) ? sd[t - o] : 0;
        __syncthreads();
        sd[t] += xv;
        __syncthreads();
    }
    int ebase = bsum[b] + sd[t] - loc;  // exclusive base for this thread's 4 elems
#pragma unroll
    for (int i = 0; i < 4; i++) {
        int idx = base + t * 4 + i;
        if (idx < N) {
            off[idx] = ebase;
            cursor[idx] = ebase;
            ebase += v[i];
        }
    }
}

__global__ __launch_bounds__(256) void fill_csr(
    const int* __restrict__ src, const int* __restrict__ dst,
    int* __restrict__ cursor, int* __restrict__ esrc, int E)
{
    int e = blockIdx.x * 256 + threadIdx.x;
    if (e < E) {
        int p = atomicAdd(&cursor[dst[e]], 1);
        esrc[p] = src[e];
    }
}

// ================= gather aggregation: agg[n] = sum_{j in CSR(n)} x[esrc[j]] =====
// 32 lanes per node; lane handles one float4 column chunk.
__global__ __launch_bounds__(256) void gather_agg(
    const float* __restrict__ xin, const int* __restrict__ off,
    const int* __restrict__ esrc, float* __restrict__ agg, int N)
{
    int lane = threadIdx.x & 31;
    int node = (blockIdx.x * 256 + threadIdx.x) >> 5;
    if (node >= N) return;
    int beg = off[node], end = off[node + 1];
    int c4 = lane << 2;
    float4 acc = make_float4(0.f, 0.f, 0.f, 0.f);
    for (int j0 = beg; j0 < end; j0 += 32) {
        int myidx = (j0 + lane < end) ? esrc[j0 + lane] : 0;
        int cnt = min(32, end - j0);
        for (int tt = 0; tt < cnt; tt++) {
            int s = __shfl(myidx, tt, 32);
            float4 v = *(const float4*)(xin + (size_t)s * HF + c4);
            acc.x += v.x;
            acc.y += v.y;
            acc.z += v.z;
            acc.w += v.w;
        }
    }
    *(float4*)(agg + (size_t)node * HF + c4) = acc;
}

// ---------------- GEMM: out = relu(U @ W + b), U = (1+eps)*X + AGG (optional fuse)
template <bool FUSE_IN>
__global__ __launch_bounds__(256) void gemm_relu(
    const float* __restrict__ X, const float* __restrict__ AGG,
    const float* __restrict__ epsp,
    const float* __restrict__ W, const float* __restrict__ bias,
    float* __restrict__ out, int n)
{
    __shared__ float u[32][HF];
    int row0 = blockIdx.x * 32;
    int tid = threadIdx.x;
    float epsv = FUSE_IN ? (1.0f + epsp[0]) : 0.0f;

    for (int s = tid; s < 1024; s += 256) {
        int r = s >> 5;
        int c4 = (s & 31) << 2;
        int row = row0 + r;
        float4 v;
        if (row < n) {
            v = *(const float4*)(X + (size_t)row * HF + c4);
            if (FUSE_IN) {
                float4 a = *(const float4*)(AGG + (size_t)row * HF + c4);
                v.x = epsv * v.x + a.x;
                v.y = epsv * v.y + a.y;
                v.z = epsv * v.z + a.z;
                v.w = epsv * v.w + a.w;
            }
        } else {
            v = make_float4(0.f, 0.f, 0.f, 0.f);
        }
        *(float4*)(&u[r][c4]) = v;
    }
    __syncthreads();

    int col0 = (tid & 31) << 2;
    int r0 = (tid >> 5) << 2;
    float acc[4][4] = {};
#pragma unroll 4
    for (int k = 0; k < HF; k += 4) {
        float4 w0 = *(const float4*)(W + (size_t)(k + 0) * HF + col0);
        float4 w1 = *(const float4*)(W + (size_t)(k + 1) * HF + col0);
        float4 w2 = *(const float4*)(W + (size_t)(k + 2) * HF + col0);
        float4 w3 = *(const float4*)(W + (size_t)(k + 3) * HF + col0);
#pragma unroll
        for (int i = 0; i < 4; i++) {
            float4 uv = *(const float4*)(&u[r0 + i][k]);
            acc[i][0] += uv.x * w0.x + uv.y * w1.x + uv.z * w2.x + uv.w * w3.x;
            acc[i][1] += uv.x * w0.y + uv.y * w1.y + uv.z * w2.y + uv.w * w3.y;
            acc[i][2] += uv.x * w0.z + uv.y * w1.z + uv.z * w2.z + uv.w * w3.z;
            acc[i][3] += uv.x * w0.w + uv.y * w1.w + uv.z * w2.w + uv.w * w3.w;
        }
    }
    float4 bv = *(const float4*)(bias + col0);
#pragma unroll
    for (int i = 0; i < 4; i++) {
        int row = row0 + r0 + i;
        if (row < n) {
            float4 o;
            o.x = fmaxf(acc[i][0] + bv.x, 0.f);
            o.y = fmaxf(acc[i][1] + bv.y, 0.f);
            o.z = fmaxf(acc[i][2] + bv.z, 0.f);
            o.w = fmaxf(acc[i][3] + bv.w, 0.f);
            *(float4*)(out + (size_t)row * HF + col0) = o;
        }
    }
}

// ---------------- BN column stats
__global__ void bn_stats(const float* __restrict__ h, float* __restrict__ S1,
                         float* __restrict__ S2, int n)
{
    int col = threadIdx.x;  // 128 threads
    float s = 0.f, q = 0.f;
    for (int r = blockIdx.x; r < n; r += gridDim.x) {
        float v = h[(size_t)r * HF + col];
        s += v;
        q += v * v;
    }
    atomicAdd(&S1[col], s);
    atomicAdd(&S2[col], q);
}

__global__ void bn_finalize(const float* __restrict__ S1, const float* __restrict__ S2,
                            const float* __restrict__ gamma, const float* __restrict__ beta,
                            float* __restrict__ scale, float* __restrict__ shift, float invN)
{
    int c = threadIdx.x;  // 128
    float mu = S1[c] * invN;
    float var = S2[c] * invN - mu * mu;
    float rs = rsqrtf(var + 1e-5f);
    float sc = gamma[c] * rs;
    scale[c] = sc;
    shift[c] = beta[c] - mu * sc;
}

__global__ __launch_bounds__(256) void bn_apply(
    const float* __restrict__ in, const float* __restrict__ scale,
    const float* __restrict__ shift, float* __restrict__ out, int total4)
{
    int i = blockIdx.x * 256 + threadIdx.x;
    if (i >= total4) return;
    int c4 = (i & 31) << 2;
    float4 v = ((const float4*)in)[i];
    float4 sc = *(const float4*)(scale + c4);
    float4 sh = *(const float4*)(shift + c4);
    v.x = v.x * sc.x + sh.x;
    v.y = v.y * sc.y + sh.y;
    v.z = v.z * sc.z + sh.z;
    v.w = v.w * sc.w + sh.w;
    ((float4*)out)[i] = v;
}

// ---------------- layer-2 tail: BN apply + pool atomics + mse, fused per node
__global__ __launch_bounds__(256) void finalize_nodes(
    const float* __restrict__ t4, const float* __restrict__ scale,
    const float* __restrict__ shift, const int* __restrict__ batch,
    const float* __restrict__ degree, const float* __restrict__ Wloss,
    const float* __restrict__ blossp, float* __restrict__ sums,
    float* __restrict__ cnt, float* __restrict__ mse_acc, int n)
{
    int lane = threadIdx.x & 63;
    int wv = threadIdx.x >> 6;
    int node = blockIdx.x * 4 + wv;
    if (node >= n) return;
    int b = batch[node];
    const float* row = t4 + (size_t)node * HF;
    float m = 0.f;
#pragma unroll
    for (int h = 0; h < 2; h++) {
        int f = lane + h * 64;
        float v = row[f] * scale[f] + shift[f];
        atomicAdd(&sums[(size_t)b * HF + f], v);
        m += v * Wloss[f];
    }
#pragma unroll
    for (int off = 32; off > 0; off >>= 1) m += __shfl_down(m, off);
    if (lane == 0) {
        float d = m + blossp[0] - degree[node];
        atomicAdd(mse_acc, d * d);
        atomicAdd(cnt + b, 1.0f);
    }
}

// ---------------- pool divide + z = relu(g @ Wlin1 + blin1)
__global__ void pool_lin1(const float* __restrict__ sums, const float* __restrict__ cnt,
                          const float* __restrict__ W, const float* __restrict__ bias,
                          float* __restrict__ z)
{
    __shared__ float gv[HF];
    int gid = blockIdx.x;
    int c = threadIdx.x;  // 128
    float inv = 1.0f / fmaxf(cnt[gid], 1.0f);
    gv[c] = sums[(size_t)gid * HF + c] * inv;
    __syncthreads();
    float a = bias[c];
#pragma unroll 8
    for (int k = 0; k < HF; k++) a += gv[k] * W[(size_t)k * HF + c];
    z[(size_t)gid * HF + c] = fmaxf(a, 0.f);
}

// ---------------- heads
__global__ void heads(const float* __restrict__ z, const float* __restrict__ W2,
                      const float* __restrict__ b2, const float* __restrict__ W4,
                      const float* __restrict__ b4, float* __restrict__ out1,
                      float* __restrict__ out3, int C_, int D_)
{
    __shared__ float zr[HF];
    __shared__ float logits[16];
    __shared__ float lse_s;
    int gid = blockIdx.x;
    int t = threadIdx.x;  // 64
    zr[t] = z[(size_t)gid * HF + t];
    zr[t + 64] = z[(size_t)gid * HF + t + 64];
    __syncthreads();
    if (t < C_) {
        float a = b2[t];
        for (int k = 0; k < HF; k++) a += zr[k] * W2[(size_t)k * C_ + t];
        logits[t] = a;
    }
    __syncthreads();
    if (t == 0) {
        float mx = -1e30f;
        for (int i = 0; i < C_; i++) mx = fmaxf(mx, logits[i]);
        float s = 0.f;
        for (int i = 0; i < C_; i++) s += expf(logits[i] - mx);
        lse_s = mx + logf(s);
    }
    __syncthreads();
    if (t < C_) out1[(size_t)gid * C_ + t] = logits[t] - lse_s;
    if (t < D_) {
        float a = b4[t];
        for (int k = 0; k < HF; k++) a += zr[k] * W4[(size_t)k * D_ + t];
        out3[(size_t)gid * D_ + t] = a;
    }
}

__global__ void mse_final(const float* __restrict__ acc, float* __restrict__ out, float invN)
{
    out[0] = acc[0] * invN;
}

extern "C" void kernel_launch(void* const* d_in, const int* in_sizes, int n_in,
                              void* d_out, int out_size, void* d_ws, size_t ws_size,
                              hipStream_t stream)
{
    const float* x      = (const float*)d_in[0];
    const int*   ei     = (const int*)d_in[1];
    const int*   batch  = (const int*)d_in[2];
    const float* degree = (const float*)d_in[3];
    const float* eps1   = (const float*)d_in[4];
    const float* W1a    = (const float*)d_in[5];
    const float* b1a    = (const float*)d_in[6];
    const float* W1b    = (const float*)d_in[7];
    const float* b1b    = (const float*)d_in[8];
    const float* g1     = (const float*)d_in[9];
    const float* be1    = (const float*)d_in[10];
    const float* eps2   = (const float*)d_in[11];
    const float* W2a    = (const float*)d_in[12];
    const float* b2a    = (const float*)d_in[13];
    const float* W2b    = (const float*)d_in[14];
    const float* b2b    = (const float*)d_in[15];
    const float* g2     = (const float*)d_in[16];
    const float* be2    = (const float*)d_in[17];
    const float* Wlin1  = (const float*)d_in[18];
    const float* blin1  = (const float*)d_in[19];
    const float* Wlin2  = (const float*)d_in[20];
    const float* blin2  = (const float*)d_in[21];
    const float* Wlin4  = (const float*)d_in[22];
    const float* blin4  = (const float*)d_in[23];
    const float* Wloss  = (const float*)d_in[24];
    const float* bloss  = (const float*)d_in[25];

    const int N  = in_sizes[0] / HF;
    const int E  = in_sizes[1] / 2;
    const int C_ = in_sizes[21];
    const int D_ = in_sizes[23];
    const int Gn = (out_size - 1) / (C_ + D_);

    const int* src = ei;
    const int* dst = ei + E;

    float* ws = (float*)d_ws;
    size_t NH = (size_t)N * HF;
    float* A  = ws;            // agg (L1), then agg2 (L2, = pre-BN h2 after gemms)
    float* B  = A + NH;        // t1, then t3
    float* Cb = B + NH;        // h1 (in place after bn_apply)
    float* S1 = Cb + NH;
    float* S2 = S1 + HF;
    float* scale = S2 + HF;
    float* shift = scale + HF;
    float* sums  = shift + HF;
    float* cnt   = sums + (size_t)Gn * HF;
    float* macc  = cnt + Gn;
    float* z     = macc + 1;
    // integer CSR arrays after z (z has Gn*HF floats)
    int* ibase  = (int*)(z + (size_t)Gn * HF);
    int* deg    = ibase;            // N (also reused as cursor)
    int* off    = deg + N;          // N+1
    int* esrc   = off + N + 1;      // E
    int* bsum   = esrc + E;         // ~128

    float* out1 = (float*)d_out;
    float* out3 = out1 + (size_t)Gn * C_;
    float* outm = out3 + (size_t)Gn * D_;

    int eBlocks    = (E + 255) / 256;
    int nb         = (N + 1023) / 1024;
    int gatherBlk  = (N * 32 + 255) / 256;
    int gemmBlocks = (N + 31) / 32;
    float invN = 1.0f / (float)N;

    // ---- build CSR (once per launch; reused by both layers) ----
    hipMemsetAsync(deg, 0, N * sizeof(int), stream);
    deg_count<<<eBlocks, 256, 0, stream>>>(dst, deg, E);
    scan_block_sums<<<nb, 256, 0, stream>>>(deg, bsum, N);
    scan_bsum<<<1, 64, 0, stream>>>(bsum, nb, off, N);
    scan_final<<<nb, 256, 0, stream>>>(deg, bsum, off, /*cursor=*/deg, N);
    fill_csr<<<eBlocks, 256, 0, stream>>>(src, dst, /*cursor=*/deg, esrc, E);

    // ---- layer 1 ----
    gather_agg<<<gatherBlk, 256, 0, stream>>>(x, off, esrc, A, N);
    gemm_relu<true><<<gemmBlocks, 256, 0, stream>>>(x, A, eps1, W1a, b1a, B, N);
    gemm_relu<false><<<gemmBlocks, 256, 0, stream>>>(B, nullptr, nullptr, W1b, b1b, Cb, N);
    hipMemsetAsync(S1, 0, 2 * HF * sizeof(float), stream);
    bn_stats<<<512, 128, 0, stream>>>(Cb, S1, S2, N);
    bn_finalize<<<1, 128, 0, stream>>>(S1, S2, g1, be1, scale, shift, invN);
    bn_apply<<<(N * 32 + 255) / 256, 256, 0, stream>>>(Cb, scale, shift, Cb, N * 32);

    // ---- layer 2 ----
    gather_agg<<<gatherBlk, 256, 0, stream>>>(Cb, off, esrc, A, N);
    gemm_relu<true><<<gemmBlocks, 256, 0, stream>>>(Cb, A, eps2, W2a, b2a, B, N);
    gemm_relu<false><<<gemmBlocks, 256, 0, stream>>>(B, nullptr, nullptr, W2b, b2b, A, N);
    hipMemsetAsync(S1, 0, 2 * HF * sizeof(float), stream);
    bn_stats<<<512, 128, 0, stream>>>(A, S1, S2, N);
    bn_finalize<<<1, 128, 0, stream>>>(S1, S2, g2, be2, scale, shift, invN);

    // ---- tail ----
    hipMemsetAsync(sums, 0, ((size_t)Gn * HF + Gn + 1) * sizeof(float), stream);
    finalize_nodes<<<(N + 3) / 4, 256, 0, stream>>>(A, scale, shift, batch, degree,
                                                    Wloss, bloss, sums, cnt, macc, N);
    pool_lin1<<<Gn, 128, 0, stream>>>(sums, cnt, Wlin1, blin1, z);
    heads<<<Gn, 64, 0, stream>>>(z, Wlin2, blin2, Wlin4, blin4, out1, out3, C_, D_);
    mse_final<<<1, 1, 0, stream>>>(macc, outm, invN);
}

// Round 3
// 1289.942 us; speedup vs baseline: 5.7466x; 1.9372x over previous
//
#include <hip/hip_runtime.h>
#include <hip/hip_bf16.h>

#define HF 128  // feature/hidden dim (F == H == 128)

// ================= CSR build =================
__global__ __launch_bounds__(256) void deg_count(
    const int* __restrict__ dst, int* __restrict__ deg, int E)
{
    int e = blockIdx.x * 256 + threadIdx.x;
    if (e < E) atomicAdd(&deg[dst[e]], 1);
}

__global__ __launch_bounds__(256) void scan_block_sums(
    const int* __restrict__ deg, int* __restrict__ bsum, int N)
{
    __shared__ int sdata[256];
    int b = blockIdx.x, t = threadIdx.x;
    int base = b * 1024;
    int s = 0;
    for (int i = t; i < 1024; i += 256) {
        int idx = base + i;
        s += (idx < N) ? deg[idx] : 0;
    }
    sdata[t] = s;
    __syncthreads();
    for (int off = 128; off > 0; off >>= 1) {
        if (t < off) sdata[t] += sdata[t + off];
        __syncthreads();
    }
    if (t == 0) bsum[b] = sdata[0];
}

__global__ void scan_bsum(int* __restrict__ bsum, int nb, int* __restrict__ off, int N)
{
    if (threadIdx.x == 0) {
        int acc = 0;
        for (int i = 0; i < nb; i++) {
            int v = bsum[i];
            bsum[i] = acc;
            acc += v;
        }
        off[N] = acc;
    }
}

__global__ __launch_bounds__(256) void scan_final(
    const int* __restrict__ deg, const int* __restrict__ bsum,
    int* __restrict__ off, int* __restrict__ cursor, int N)
{
    __shared__ int sd[256];
    int b = blockIdx.x, t = threadIdx.x;
    int base = b * 1024;
    int v[4];
    int loc = 0;
#pragma unroll
    for (int i = 0; i < 4; i++) {
        int idx = base + t * 4 + i;
        v[i] = (idx < N) ? deg[idx] : 0;
        loc += v[i];
    }
    sd[t] = loc;
    __syncthreads();
    for (int o = 1; o < 256; o <<= 1) {
        int xv = (t >= o) ? sd[t - o] : 0;
        __syncthreads();
        sd[t] += xv;
        __syncthreads();
    }
    int ebase = bsum[b] + sd[t] - loc;
#pragma unroll
    for (int i = 0; i < 4; i++) {
        int idx = base + t * 4 + i;
        if (idx < N) {
            off[idx] = ebase;
            cursor[idx] = ebase;
            ebase += v[i];
        }
    }
}

__global__ __launch_bounds__(256) void fill_csr(
    const int* __restrict__ src, const int* __restrict__ dst,
    int* __restrict__ cursor, int* __restrict__ esrc, int E)
{
    int e = blockIdx.x * 256 + threadIdx.x;
    if (e < E) {
        int p = atomicAdd(&cursor[dst[e]], 1);
        esrc[p] = src[e];
    }
}

// ================= gather aggregation =================
__global__ __launch_bounds__(256) void gather_agg(
    const float* __restrict__ xin, const int* __restrict__ off,
    const int* __restrict__ esrc, float* __restrict__ agg, int N)
{
    int lane = threadIdx.x & 31;
    int node = (blockIdx.x * 256 + threadIdx.x) >> 5;
    if (node >= N) return;
    int beg = off[node], end = off[node + 1];
    int c4 = lane << 2;
    float4 acc = make_float4(0.f, 0.f, 0.f, 0.f);
    for (int j0 = beg; j0 < end; j0 += 32) {
        int myidx = (j0 + lane < end) ? esrc[j0 + lane] : 0;
        int cnt = min(32, end - j0);
        for (int tt = 0; tt < cnt; tt++) {
            int s = __shfl(myidx, tt, 32);
            float4 v = *(const float4*)(xin + (size_t)s * HF + c4);
            acc.x += v.x;
            acc.y += v.y;
            acc.z += v.z;
            acc.w += v.w;
        }
    }
    *(float4*)(agg + (size_t)node * HF + c4) = acc;
}

// ---------------- GEMM: out = relu(U @ W + b), U = (1+eps)*X + AGG (optional fuse)
template <bool FUSE_IN>
__global__ __launch_bounds__(256) void gemm_relu(
    const float* __restrict__ X, const float* __restrict__ AGG,
    const float* __restrict__ epsp,
    const float* __restrict__ W, const float* __restrict__ bias,
    float* __restrict__ out, int n)
{
    __shared__ float u[32][HF];
    int row0 = blockIdx.x * 32;
    int tid = threadIdx.x;
    float epsv = FUSE_IN ? (1.0f + epsp[0]) : 0.0f;

    for (int s = tid; s < 1024; s += 256) {
        int r = s >> 5;
        int c4 = (s & 31) << 2;
        int row = row0 + r;
        float4 v;
        if (row < n) {
            v = *(const float4*)(X + (size_t)row * HF + c4);
            if (FUSE_IN) {
                float4 a = *(const float4*)(AGG + (size_t)row * HF + c4);
                v.x = epsv * v.x + a.x;
                v.y = epsv * v.y + a.y;
                v.z = epsv * v.z + a.z;
                v.w = epsv * v.w + a.w;
            }
        } else {
            v = make_float4(0.f, 0.f, 0.f, 0.f);
        }
        *(float4*)(&u[r][c4]) = v;
    }
    __syncthreads();

    int col0 = (tid & 31) << 2;
    int r0 = (tid >> 5) << 2;
    float acc[4][4] = {};
#pragma unroll 4
    for (int k = 0; k < HF; k += 4) {
        float4 w0 = *(const float4*)(W + (size_t)(k + 0) * HF + col0);
        float4 w1 = *(const float4*)(W + (size_t)(k + 1) * HF + col0);
        float4 w2 = *(const float4*)(W + (size_t)(k + 2) * HF + col0);
        float4 w3 = *(const float4*)(W + (size_t)(k + 3) * HF + col0);
#pragma unroll
        for (int i = 0; i < 4; i++) {
            float4 uv = *(const float4*)(&u[r0 + i][k]);
            acc[i][0] += uv.x * w0.x + uv.y * w1.x + uv.z * w2.x + uv.w * w3.x;
            acc[i][1] += uv.x * w0.y + uv.y * w1.y + uv.z * w2.y + uv.w * w3.y;
            acc[i][2] += uv.x * w0.z + uv.y * w1.z + uv.z * w2.z + uv.w * w3.z;
            acc[i][3] += uv.x * w0.w + uv.y * w1.w + uv.z * w2.w + uv.w * w3.w;
        }
    }
    float4 bv = *(const float4*)(bias + col0);
#pragma unroll
    for (int i = 0; i < 4; i++) {
        int row = row0 + r0 + i;
        if (row < n) {
            float4 o;
            o.x = fmaxf(acc[i][0] + bv.x, 0.f);
            o.y = fmaxf(acc[i][1] + bv.y, 0.f);
            o.z = fmaxf(acc[i][2] + bv.z, 0.f);
            o.w = fmaxf(acc[i][3] + bv.w, 0.f);
            *(float4*)(out + (size_t)row * HF + col0) = o;
        }
    }
}

// ---------------- BN column stats
__global__ void bn_stats(const float* __restrict__ h, float* __restrict__ S1,
                         float* __restrict__ S2, int n)
{
    int col = threadIdx.x;  // 128 threads
    float s = 0.f, q = 0.f;
    for (int r = blockIdx.x; r < n; r += gridDim.x) {
        float v = h[(size_t)r * HF + col];
        s += v;
        q += v * v;
    }
    atomicAdd(&S1[col], s);
    atomicAdd(&S2[col], q);
}

__global__ void bn_finalize(const float* __restrict__ S1, const float* __restrict__ S2,
                            const float* __restrict__ gamma, const float* __restrict__ beta,
                            float* __restrict__ scale, float* __restrict__ shift, float invN)
{
    int c = threadIdx.x;  // 128
    float mu = S1[c] * invN;
    float var = S2[c] * invN - mu * mu;
    float rs = rsqrtf(var + 1e-5f);
    float sc = gamma[c] * rs;
    scale[c] = sc;
    shift[c] = beta[c] - mu * sc;
}

__global__ __launch_bounds__(256) void bn_apply(
    const float* __restrict__ in, const float* __restrict__ scale,
    const float* __restrict__ shift, float* __restrict__ out, int total4)
{
    int i = blockIdx.x * 256 + threadIdx.x;
    if (i >= total4) return;
    int c4 = (i & 31) << 2;
    float4 v = ((const float4*)in)[i];
    float4 sc = *(const float4*)(scale + c4);
    float4 sh = *(const float4*)(shift + c4);
    v.x = v.x * sc.x + sh.x;
    v.y = v.y * sc.y + sh.y;
    v.z = v.z * sc.z + sh.z;
    v.w = v.w * sc.w + sh.w;
    ((float4*)out)[i] = v;
}

// ---------------- graph segment bounds (batch is sorted) ----------------
__global__ __launch_bounds__(256) void graph_bounds(
    const int* __restrict__ batch, int* __restrict__ gstart, int N, int Gn)
{
    int i = blockIdx.x * 256 + threadIdx.x;
    if (i >= N) return;
    int bi = batch[i];
    int bp = (i == 0) ? -1 : batch[i - 1];
    for (int g = bp + 1; g <= bi; g++) gstart[g] = i;
    if (i == N - 1) {
        for (int g = bi + 1; g <= Gn; g++) gstart[g] = N;
    }
}

// ---------------- pooled mean (BN2 affine folded) + z = relu(g @ Wlin1 + blin1)
// One block (128 threads) per graph; contiguous node range, no atomics.
__global__ void pool_lin1(const float* __restrict__ h2raw, const float* __restrict__ scale,
                          const float* __restrict__ shift, const int* __restrict__ gstart,
                          const float* __restrict__ W, const float* __restrict__ bias,
                          float* __restrict__ z)
{
    __shared__ float gv[HF];
    int gid = blockIdx.x;
    int c = threadIdx.x;  // 128
    int b = gstart[gid], e = gstart[gid + 1];
    float s = 0.f;
    for (int r = b; r < e; r++) s += h2raw[(size_t)r * HF + c];
    float g = 0.f;
    if (e > b) g = scale[c] * (s / (float)(e - b)) + shift[c];
    gv[c] = g;
    __syncthreads();
    float a = bias[c];
#pragma unroll 8
    for (int k = 0; k < HF; k++) a += gv[k] * W[(size_t)k * HF + c];
    z[(size_t)gid * HF + c] = fmaxf(a, 0.f);
}

// ---------------- mse partials: BN2 folded into loss weights; no hot atomics
__global__ __launch_bounds__(256) void mse_partial(
    const float* __restrict__ h2raw, const float* __restrict__ scale,
    const float* __restrict__ shift, const float* __restrict__ Wloss,
    const float* __restrict__ blossp, const float* __restrict__ degree,
    float* __restrict__ partial, int N)
{
    __shared__ float red[4];
    int lane = threadIdx.x & 63;
    int wv = threadIdx.x >> 6;
    float wl0 = scale[lane] * Wloss[lane];
    float wl1 = scale[lane + 64] * Wloss[lane + 64];
    float c0l = shift[lane] * Wloss[lane] + shift[lane + 64] * Wloss[lane + 64];
    float bl = blossp[0];
    float acc = 0.f;
    for (int node = blockIdx.x * 4 + wv; node < N; node += gridDim.x * 4) {
        const float* row = h2raw + (size_t)node * HF;
        float m = row[lane] * wl0 + row[lane + 64] * wl1 + c0l;
#pragma unroll
        for (int off = 32; off > 0; off >>= 1) m += __shfl_down(m, off);
        if (lane == 0) {
            float d = m + bl - degree[node];
            acc += d * d;
        }
    }
    if (lane == 0) red[wv] = acc;
    __syncthreads();
    if (threadIdx.x == 0)
        partial[blockIdx.x] = red[0] + red[1] + red[2] + red[3];
}

__global__ void mse_final(const float* __restrict__ partial, float* __restrict__ out,
                          float invN, int P)
{
    __shared__ float sd[256];
    int t = threadIdx.x;
    float s = 0.f;
    for (int i = t; i < P; i += 256) s += partial[i];
    sd[t] = s;
    __syncthreads();
    for (int o = 128; o > 0; o >>= 1) {
        if (t < o) sd[t] += sd[t + o];
        __syncthreads();
    }
    if (t == 0) out[0] = sd[0] * invN;
}

// ---------------- heads
__global__ void heads(const float* __restrict__ z, const float* __restrict__ W2,
                      const float* __restrict__ b2, const float* __restrict__ W4,
                      const float* __restrict__ b4, float* __restrict__ out1,
                      float* __restrict__ out3, int C_, int D_)
{
    __shared__ float zr[HF];
    __shared__ float logits[16];
    __shared__ float lse_s;
    int gid = blockIdx.x;
    int t = threadIdx.x;  // 64
    zr[t] = z[(size_t)gid * HF + t];
    zr[t + 64] = z[(size_t)gid * HF + t + 64];
    __syncthreads();
    if (t < C_) {
        float a = b2[t];
        for (int k = 0; k < HF; k++) a += zr[k] * W2[(size_t)k * C_ + t];
        logits[t] = a;
    }
    __syncthreads();
    if (t == 0) {
        float mx = -1e30f;
        for (int i = 0; i < C_; i++) mx = fmaxf(mx, logits[i]);
        float s = 0.f;
        for (int i = 0; i < C_; i++) s += expf(logits[i] - mx);
        lse_s = mx + logf(s);
    }
    __syncthreads();
    if (t < C_) out1[(size_t)gid * C_ + t] = logits[t] - lse_s;
    if (t < D_) {
        float a = b4[t];
        for (int k = 0; k < HF; k++) a += zr[k] * W4[(size_t)k * D_ + t];
        out3[(size_t)gid * D_ + t] = a;
    }
}

extern "C" void kernel_launch(void* const* d_in, const int* in_sizes, int n_in,
                              void* d_out, int out_size, void* d_ws, size_t ws_size,
                              hipStream_t stream)
{
    const float* x      = (const float*)d_in[0];
    const int*   ei     = (const int*)d_in[1];
    const int*   batch  = (const int*)d_in[2];
    const float* degree = (const float*)d_in[3];
    const float* eps1   = (const float*)d_in[4];
    const float* W1a    = (const float*)d_in[5];
    const float* b1a    = (const float*)d_in[6];
    const float* W1b    = (const float*)d_in[7];
    const float* b1b    = (const float*)d_in[8];
    const float* g1     = (const float*)d_in[9];
    const float* be1    = (const float*)d_in[10];
    const float* eps2   = (const float*)d_in[11];
    const float* W2a    = (const float*)d_in[12];
    const float* b2a    = (const float*)d_in[13];
    const float* W2b    = (const float*)d_in[14];
    const float* b2b    = (const float*)d_in[15];
    const float* g2     = (const float*)d_in[16];
    const float* be2    = (const float*)d_in[17];
    const float* Wlin1  = (const float*)d_in[18];
    const float* blin1  = (const float*)d_in[19];
    const float* Wlin2  = (const float*)d_in[20];
    const float* blin2  = (const float*)d_in[21];
    const float* Wlin4  = (const float*)d_in[22];
    const float* blin4  = (const float*)d_in[23];
    const float* Wloss  = (const float*)d_in[24];
    const float* bloss  = (const float*)d_in[25];

    const int N  = in_sizes[0] / HF;
    const int E  = in_sizes[1] / 2;
    const int C_ = in_sizes[21];
    const int D_ = in_sizes[23];
    const int Gn = (out_size - 1) / (C_ + D_);

    const int* src = ei;
    const int* dst = ei + E;

    float* ws = (float*)d_ws;
    size_t NH = (size_t)N * HF;
    float* A  = ws;            // agg (L1), then agg2 (L2, = pre-BN h2 after gemms)
    float* B  = A + NH;        // t1, then t3
    float* Cb = B + NH;        // h1 (in place after bn_apply)
    float* S1 = Cb + NH;
    float* S2 = S1 + HF;
    float* scale = S2 + HF;
    float* shift = scale + HF;
    float* z     = shift + HF;                    // Gn*HF
    float* partial = z + (size_t)Gn * HF;         // 1024
    int* ibase  = (int*)(partial + 1024);
    int* gstart = ibase;            // Gn+1
    int* deg    = gstart + Gn + 1;  // N (also reused as cursor)
    int* off    = deg + N;          // N+1
    int* esrc   = off + N + 1;      // E
    int* bsum   = esrc + E;         // ~128

    float* out1 = (float*)d_out;
    float* out3 = out1 + (size_t)Gn * C_;
    float* outm = out3 + (size_t)Gn * D_;

    int eBlocks    = (E + 255) / 256;
    int nBlocks    = (N + 255) / 256;
    int nb         = (N + 1023) / 1024;
    int gatherBlk  = (N * 32 + 255) / 256;
    int gemmBlocks = (N + 31) / 32;
    const int P    = 1024;
    float invN = 1.0f / (float)N;

    // ---- build CSR + graph bounds (once per launch) ----
    hipMemsetAsync(deg, 0, N * sizeof(int), stream);
    deg_count<<<eBlocks, 256, 0, stream>>>(dst, deg, E);
    scan_block_sums<<<nb, 256, 0, stream>>>(deg, bsum, N);
    scan_bsum<<<1, 64, 0, stream>>>(bsum, nb, off, N);
    scan_final<<<nb, 256, 0, stream>>>(deg, bsum, off, /*cursor=*/deg, N);
    fill_csr<<<eBlocks, 256, 0, stream>>>(src, dst, /*cursor=*/deg, esrc, E);
    graph_bounds<<<nBlocks, 256, 0, stream>>>(batch, gstart, N, Gn);

    // ---- layer 1 ----
    gather_agg<<<gatherBlk, 256, 0, stream>>>(x, off, esrc, A, N);
    gemm_relu<true><<<gemmBlocks, 256, 0, stream>>>(x, A, eps1, W1a, b1a, B, N);
    gemm_relu<false><<<gemmBlocks, 256, 0, stream>>>(B, nullptr, nullptr, W1b, b1b, Cb, N);
    hipMemsetAsync(S1, 0, 2 * HF * sizeof(float), stream);
    bn_stats<<<512, 128, 0, stream>>>(Cb, S1, S2, N);
    bn_finalize<<<1, 128, 0, stream>>>(S1, S2, g1, be1, scale, shift, invN);
    bn_apply<<<(N * 32 + 255) / 256, 256, 0, stream>>>(Cb, scale, shift, Cb, N * 32);

    // ---- layer 2 (BN2 never materialized; folded into tail) ----
    gather_agg<<<gatherBlk, 256, 0, stream>>>(Cb, off, esrc, A, N);
    gemm_relu<true><<<gemmBlocks, 256, 0, stream>>>(Cb, A, eps2, W2a, b2a, B, N);
    gemm_relu<false><<<gemmBlocks, 256, 0, stream>>>(B, nullptr, nullptr, W2b, b2b, A, N);
    hipMemsetAsync(S1, 0, 2 * HF * sizeof(float), stream);
    bn_stats<<<512, 128, 0, stream>>>(A, S1, S2, N);
    bn_finalize<<<1, 128, 0, stream>>>(S1, S2, g2, be2, scale, shift, invN);

    // ---- tail: segment pooling (no atomics) + folded mse + heads ----
    pool_lin1<<<Gn, 128, 0, stream>>>(A, scale, shift, gstart, Wlin1, blin1, z);
    mse_partial<<<P, 256, 0, stream>>>(A, scale, shift, Wloss, bloss, degree, partial, N);
    mse_final<<<1, 256, 0, stream>>>(partial, outm, invN, P);
    heads<<<Gn, 64, 0, stream>>>(z, Wlin2, blin2, Wlin4, blin4, out1, out3, C_, D_);
}

// Round 4
// 836.670 us; speedup vs baseline: 8.8598x; 1.5418x over previous
//
#include <hip/hip_runtime.h>
#include <hip/hip_bf16.h>

#define HF 128  // feature/hidden dim (F == H == 128)

typedef __attribute__((ext_vector_type(8))) short bf16x8;
typedef __attribute__((ext_vector_type(4))) float f32x4;

__device__ inline float bflo(unsigned u) { return __uint_as_float(u << 16); }
__device__ inline float bfhi(unsigned u) { return __uint_as_float(u & 0xffff0000u); }
__device__ inline unsigned short f2bf(float f) {
    unsigned u = __float_as_uint(f);
    unsigned r = (u + 0x7fffu + ((u >> 16) & 1u)) >> 16;
    return (unsigned short)r;
}
__device__ inline unsigned pack2(float a, float b) {
    return (unsigned)f2bf(a) | ((unsigned)f2bf(b) << 16);
}

// ================= casts =================
__global__ __launch_bounds__(256) void cast_x(
    const float* __restrict__ x, unsigned short* __restrict__ xb, int nchunks)
{
    int i = blockIdx.x * 256 + threadIdx.x;
    if (i >= nchunks) return;
    float4 a = ((const float4*)x)[2 * i];
    float4 b = ((const float4*)x)[2 * i + 1];
    uint4 o;
    o.x = pack2(a.x, a.y); o.y = pack2(a.z, a.w);
    o.z = pack2(b.x, b.y); o.w = pack2(b.z, b.w);
    ((uint4*)xb)[i] = o;
}

// transpose-cast 4 weights: Wt[n*128+k] = W[k*128+n]
__global__ void cast_wt(const float* __restrict__ w0, const float* __restrict__ w1,
                        const float* __restrict__ w2, const float* __restrict__ w3,
                        unsigned short* __restrict__ out)
{
    const float* W = (blockIdx.x == 0) ? w0 : (blockIdx.x == 1) ? w1
                   : (blockIdx.x == 2) ? w2 : w3;
    unsigned short* O = out + blockIdx.x * 16384;
    for (int idx = threadIdx.x; idx < 16384; idx += 256) {
        int n = idx >> 7, k = idx & 127;
        O[idx] = f2bf(W[k * 128 + n]);
    }
}

// ================= CSR build =================
__global__ __launch_bounds__(256) void deg_count(
    const int* __restrict__ dst, int* __restrict__ deg, int E)
{
    int e = blockIdx.x * 256 + threadIdx.x;
    if (e < E) atomicAdd(&deg[dst[e]], 1);
}

__global__ __launch_bounds__(256) void scan_block_sums(
    const int* __restrict__ deg, int* __restrict__ bsum, int N)
{
    __shared__ int sdata[256];
    int b = blockIdx.x, t = threadIdx.x;
    int base = b * 1024;
    int s = 0;
    for (int i = t; i < 1024; i += 256) {
        int idx = base + i;
        s += (idx < N) ? deg[idx] : 0;
    }
    sdata[t] = s;
    __syncthreads();
    for (int off = 128; off > 0; off >>= 1) {
        if (t < off) sdata[t] += sdata[t + off];
        __syncthreads();
    }
    if (t == 0) bsum[b] = sdata[0];
}

__global__ void scan_bsum(int* __restrict__ bsum, int nb, int* __restrict__ off, int N)
{
    if (threadIdx.x == 0) {
        int acc = 0;
        for (int i = 0; i < nb; i++) {
            int v = bsum[i];
            bsum[i] = acc;
            acc += v;
        }
        off[N] = acc;
    }
}

__global__ __launch_bounds__(256) void scan_final(
    const int* __restrict__ deg, const int* __restrict__ bsum,
    int* __restrict__ off, int* __restrict__ cursor, int N)
{
    __shared__ int sd[256];
    int b = blockIdx.x, t = threadIdx.x;
    int base = b * 1024;
    int v[4];
    int loc = 0;
#pragma unroll
    for (int i = 0; i < 4; i++) {
        int idx = base + t * 4 + i;
        v[i] = (idx < N) ? deg[idx] : 0;
        loc += v[i];
    }
    sd[t] = loc;
    __syncthreads();
    for (int o = 1; o < 256; o <<= 1) {
        int xv = (t >= o) ? sd[t - o] : 0;
        __syncthreads();
        sd[t] += xv;
        __syncthreads();
    }
    int ebase = bsum[b] + sd[t] - loc;
#pragma unroll
    for (int i = 0; i < 4; i++) {
        int idx = base + t * 4 + i;
        if (idx < N) {
            off[idx] = ebase;
            cursor[idx] = ebase;
            ebase += v[i];
        }
    }
}

__global__ __launch_bounds__(256) void fill_csr(
    const int* __restrict__ src, const int* __restrict__ dst,
    int* __restrict__ cursor, int* __restrict__ esrc, int E)
{
    int e = blockIdx.x * 256 + threadIdx.x;
    if (e < E) {
        int p = atomicAdd(&cursor[dst[e]], 1);
        esrc[p] = src[e];
    }
}

// ============ gather + fused U = (1+eps)*x + agg, bf16 in/out ============
// 16 lanes per node; lane handles 8 bf16 columns (16 B).
__global__ __launch_bounds__(256) void gather_u(
    const unsigned short* __restrict__ xb, const int* __restrict__ off,
    const int* __restrict__ esrc, const float* __restrict__ epsp,
    unsigned short* __restrict__ Uo, int N)
{
    int lane16 = threadIdx.x & 15;
    int node = (blockIdx.x * 256 + threadIdx.x) >> 4;
    if (node >= N) return;
    int beg = off[node], end = off[node + 1];
    float acc[8] = {0.f, 0.f, 0.f, 0.f, 0.f, 0.f, 0.f, 0.f};
    for (int j0 = beg; j0 < end; j0 += 16) {
        int myidx = (j0 + lane16 < end) ? esrc[j0 + lane16] : 0;
        int cnt = min(16, end - j0);
        for (int t = 0; t < cnt; t++) {
            int s = __shfl(myidx, t, 16);
            uint4 p = *(const uint4*)(xb + (size_t)s * HF + lane16 * 8);
            acc[0] += bflo(p.x); acc[1] += bfhi(p.x);
            acc[2] += bflo(p.y); acc[3] += bfhi(p.y);
            acc[4] += bflo(p.z); acc[5] += bfhi(p.z);
            acc[6] += bflo(p.w); acc[7] += bfhi(p.w);
        }
    }
    float ep = 1.0f + epsp[0];
    uint4 xx = *(const uint4*)(xb + (size_t)node * HF + lane16 * 8);
    acc[0] += ep * bflo(xx.x); acc[1] += ep * bfhi(xx.x);
    acc[2] += ep * bflo(xx.y); acc[3] += ep * bfhi(xx.y);
    acc[4] += ep * bflo(xx.z); acc[5] += ep * bfhi(xx.z);
    acc[6] += ep * bflo(xx.w); acc[7] += ep * bfhi(xx.w);
    uint4 o;
    o.x = pack2(acc[0], acc[1]); o.y = pack2(acc[2], acc[3]);
    o.z = pack2(acc[4], acc[5]); o.w = pack2(acc[6], acc[7]);
    *(uint4*)(Uo + (size_t)node * HF + lane16 * 8) = o;
}

// ============ MFMA GEMM: out = relu(U @ W + bias), bf16 in/out, fp32 acc ====
// Block 256 thr = 4 waves; 64-row tile; wave = 32 rows x 64 cols.
// A tile + transposed W in LDS, +8 bf16 row pad (2-way bank conflicts only).
#define AST 136
__global__ __launch_bounds__(256) void gemm_mfma(
    const unsigned short* __restrict__ U, const unsigned short* __restrict__ Wt,
    const float* __restrict__ bias, unsigned short* __restrict__ out, int n)
{
    __shared__ unsigned short lA[64 * AST];
    __shared__ unsigned short lB[128 * AST];
    int tid = threadIdx.x;
    int row0 = blockIdx.x * 64;

    for (int c = tid; c < 2048; c += 256) {          // stage Wt (128x128)
        int r = c >> 4, k16 = c & 15;
        uint4 v = *(const uint4*)(Wt + r * HF + k16 * 8);
        *(uint4*)(&lB[r * AST + k16 * 8]) = v;
    }
    for (int c = tid; c < 1024; c += 256) {          // stage A (64x128)
        int r = c >> 4, k16 = c & 15;
        int grow = row0 + r;
        uint4 v = make_uint4(0u, 0u, 0u, 0u);
        if (grow < n) v = *(const uint4*)(U + (size_t)grow * HF + k16 * 8);
        *(uint4*)(&lA[r * AST + k16 * 8]) = v;
    }
    __syncthreads();

    int w = tid >> 6;
    int lane = tid & 63;
    int m = lane & 15, quad = lane >> 4;
    int wr = w & 1;        // row half: rows [32*wr, 32*wr+32)
    int wc = w >> 1;       // col half: cols [64*wc, 64*wc+64)

    f32x4 acc[2][4];
#pragma unroll
    for (int i = 0; i < 2; i++)
#pragma unroll
        for (int j = 0; j < 4; j++) acc[i][j] = (f32x4){0.f, 0.f, 0.f, 0.f};

#pragma unroll
    for (int kk = 0; kk < 4; kk++) {
        int ko = kk * 32 + quad * 8;
        bf16x8 a0 = *(const bf16x8*)(&lA[(wr * 32 + m) * AST + ko]);
        bf16x8 a1 = *(const bf16x8*)(&lA[(wr * 32 + 16 + m) * AST + ko]);
#pragma unroll
        for (int nt = 0; nt < 4; nt++) {
            bf16x8 b = *(const bf16x8*)(&lB[(wc * 64 + nt * 16 + m) * AST + ko]);
            acc[0][nt] = __builtin_amdgcn_mfma_f32_16x16x32_bf16(a0, b, acc[0][nt], 0, 0, 0);
            acc[1][nt] = __builtin_amdgcn_mfma_f32_16x16x32_bf16(a1, b, acc[1][nt], 0, 0, 0);
        }
    }

#pragma unroll
    for (int nt = 0; nt < 4; nt++) {
        int col = wc * 64 + nt * 16 + m;
        float bv = bias[col];
#pragma unroll
        for (int mt = 0; mt < 2; mt++) {
#pragma unroll
            for (int r = 0; r < 4; r++) {
                int grow = row0 + wr * 32 + mt * 16 + quad * 4 + r;
                if (grow < n) {
                    float v = fmaxf(acc[mt][nt][r] + bv, 0.f);
                    out[(size_t)grow * HF + col] = f2bf(v);
                }
            }
        }
    }
}

// ---------------- BN column stats (bf16 input, fp32 accum)
__global__ void bn_stats(const unsigned short* __restrict__ h, float* __restrict__ S1,
                         float* __restrict__ S2, int n)
{
    int col = threadIdx.x;  // 128
    float s = 0.f, q = 0.f;
    for (int r = blockIdx.x; r < n; r += gridDim.x) {
        float v = __uint_as_float(((unsigned)h[(size_t)r * HF + col]) << 16);
        s += v;
        q += v * v;
    }
    atomicAdd(&S1[col], s);
    atomicAdd(&S2[col], q);
}

__global__ void bn_finalize(const float* __restrict__ S1, const float* __restrict__ S2,
                            const float* __restrict__ gamma, const float* __restrict__ beta,
                            float* __restrict__ scale, float* __restrict__ shift, float invN)
{
    int c = threadIdx.x;  // 128
    float mu = S1[c] * invN;
    float var = S2[c] * invN - mu * mu;
    float rs = rsqrtf(var + 1e-5f);
    float sc = gamma[c] * rs;
    scale[c] = sc;
    shift[c] = beta[c] - mu * sc;
}

__global__ __launch_bounds__(256) void bn_apply(
    const unsigned short* __restrict__ in, const float* __restrict__ scale,
    const float* __restrict__ shift, unsigned short* __restrict__ out, int nchunks)
{
    int i = blockIdx.x * 256 + threadIdx.x;
    if (i >= nchunks) return;
    int c8 = (i & 15) * 8;
    uint4 p = ((const uint4*)in)[i];
    const float4 s0 = *(const float4*)(scale + c8);
    const float4 s1 = *(const float4*)(scale + c8 + 4);
    const float4 h0 = *(const float4*)(shift + c8);
    const float4 h1 = *(const float4*)(shift + c8 + 4);
    uint4 o;
    o.x = pack2(bflo(p.x) * s0.x + h0.x, bfhi(p.x) * s0.y + h0.y);
    o.y = pack2(bflo(p.y) * s0.z + h0.z, bfhi(p.y) * s0.w + h0.w);
    o.z = pack2(bflo(p.z) * s1.x + h1.x, bfhi(p.z) * s1.y + h1.y);
    o.w = pack2(bflo(p.w) * s1.z + h1.z, bfhi(p.w) * s1.w + h1.w);
    ((uint4*)out)[i] = o;
}

// ---------------- graph segment bounds (batch sorted) ----------------
__global__ __launch_bounds__(256) void graph_bounds(
    const int* __restrict__ batch, int* __restrict__ gstart, int N, int Gn)
{
    int i = blockIdx.x * 256 + threadIdx.x;
    if (i >= N) return;
    int bi = batch[i];
    int bp = (i == 0) ? -1 : batch[i - 1];
    for (int g = bp + 1; g <= bi; g++) gstart[g] = i;
    if (i == N - 1) {
        for (int g = bi + 1; g <= Gn; g++) gstart[g] = N;
    }
}

// ---------------- pooled mean (BN2 folded) + z = relu(g @ Wlin1 + blin1)
__global__ void pool_lin1(const unsigned short* __restrict__ h2raw,
                          const float* __restrict__ scale, const float* __restrict__ shift,
                          const int* __restrict__ gstart, const float* __restrict__ W,
                          const float* __restrict__ bias, float* __restrict__ z)
{
    __shared__ float gv[HF];
    int gid = blockIdx.x;
    int c = threadIdx.x;  // 128
    int b = gstart[gid], e = gstart[gid + 1];
    float s = 0.f;
    for (int r = b; r < e; r++)
        s += __uint_as_float(((unsigned)h2raw[(size_t)r * HF + c]) << 16);
    float g = 0.f;
    if (e > b) g = scale[c] * (s / (float)(e - b)) + shift[c];
    gv[c] = g;
    __syncthreads();
    float a = bias[c];
#pragma unroll 8
    for (int k = 0; k < HF; k++) a += gv[k] * W[(size_t)k * HF + c];
    z[(size_t)gid * HF + c] = fmaxf(a, 0.f);
}

// ---------------- mse partials (BN2 folded into weights)
__global__ __launch_bounds__(256) void mse_partial(
    const unsigned short* __restrict__ h2raw, const float* __restrict__ scale,
    const float* __restrict__ shift, const float* __restrict__ Wloss,
    const float* __restrict__ blossp, const float* __restrict__ degree,
    float* __restrict__ partial, int N)
{
    __shared__ float red[4];
    int lane = threadIdx.x & 63;
    int wv = threadIdx.x >> 6;
    float wl0 = scale[lane] * Wloss[lane];
    float wl1 = scale[lane + 64] * Wloss[lane + 64];
    float c0l = shift[lane] * Wloss[lane] + shift[lane + 64] * Wloss[lane + 64];
    float bl = blossp[0];
    float acc = 0.f;
    for (int node = blockIdx.x * 4 + wv; node < N; node += gridDim.x * 4) {
        const unsigned short* row = h2raw + (size_t)node * HF;
        float v0 = __uint_as_float(((unsigned)row[lane]) << 16);
        float v1 = __uint_as_float(((unsigned)row[lane + 64]) << 16);
        float m = v0 * wl0 + v1 * wl1 + c0l;
#pragma unroll
        for (int off = 32; off > 0; off >>= 1) m += __shfl_down(m, off);
        if (lane == 0) {
            float d = m + bl - degree[node];
            acc += d * d;
        }
    }
    if (lane == 0) red[wv] = acc;
    __syncthreads();
    if (threadIdx.x == 0)
        partial[blockIdx.x] = red[0] + red[1] + red[2] + red[3];
}

__global__ void mse_final(const float* __restrict__ partial, float* __restrict__ out,
                          float invN, int P)
{
    __shared__ float sd[256];
    int t = threadIdx.x;
    float s = 0.f;
    for (int i = t; i < P; i += 256) s += partial[i];
    sd[t] = s;
    __syncthreads();
    for (int o = 128; o > 0; o >>= 1) {
        if (t < o) sd[t] += sd[t + o];
        __syncthreads();
    }
    if (t == 0) out[0] = sd[0] * invN;
}

// ---------------- heads
__global__ void heads(const float* __restrict__ z, const float* __restrict__ W2,
                      const float* __restrict__ b2, const float* __restrict__ W4,
                      const float* __restrict__ b4, float* __restrict__ out1,
                      float* __restrict__ out3, int C_, int D_)
{
    __shared__ float zr[HF];
    __shared__ float logits[16];
    __shared__ float lse_s;
    int gid = blockIdx.x;
    int t = threadIdx.x;  // 64
    zr[t] = z[(size_t)gid * HF + t];
    zr[t + 64] = z[(size_t)gid * HF + t + 64];
    __syncthreads();
    if (t < C_) {
        float a = b2[t];
        for (int k = 0; k < HF; k++) a += zr[k] * W2[(size_t)k * C_ + t];
        logits[t] = a;
    }
    __syncthreads();
    if (t == 0) {
        float mx = -1e30f;
        for (int i = 0; i < C_; i++) mx = fmaxf(mx, logits[i]);
        float s = 0.f;
        for (int i = 0; i < C_; i++) s += expf(logits[i] - mx);
        lse_s = mx + logf(s);
    }
    __syncthreads();
    if (t < C_) out1[(size_t)gid * C_ + t] = logits[t] - lse_s;
    if (t < D_) {
        float a = b4[t];
        for (int k = 0; k < HF; k++) a += zr[k] * W4[(size_t)k * D_ + t];
        out3[(size_t)gid * D_ + t] = a;
    }
}

extern "C" void kernel_launch(void* const* d_in, const int* in_sizes, int n_in,
                              void* d_out, int out_size, void* d_ws, size_t ws_size,
                              hipStream_t stream)
{
    const float* x      = (const float*)d_in[0];
    const int*   ei     = (const int*)d_in[1];
    const int*   batch  = (const int*)d_in[2];
    const float* degree = (const float*)d_in[3];
    const float* eps1   = (const float*)d_in[4];
    const float* W1a    = (const float*)d_in[5];
    const float* b1a    = (const float*)d_in[6];
    const float* W1b    = (const float*)d_in[7];
    const float* b1b    = (const float*)d_in[8];
    const float* g1     = (const float*)d_in[9];
    const float* be1    = (const float*)d_in[10];
    const float* eps2   = (const float*)d_in[11];
    const float* W2a    = (const float*)d_in[12];
    const float* b2a    = (const float*)d_in[13];
    const float* W2b    = (const float*)d_in[14];
    const float* b2b    = (const float*)d_in[15];
    const float* g2     = (const float*)d_in[16];
    const float* be2    = (const float*)d_in[17];
    const float* Wlin1  = (const float*)d_in[18];
    const float* blin1  = (const float*)d_in[19];
    const float* Wlin2  = (const float*)d_in[20];
    const float* blin2  = (const float*)d_in[21];
    const float* Wlin4  = (const float*)d_in[22];
    const float* blin4  = (const float*)d_in[23];
    const float* Wloss  = (const float*)d_in[24];
    const float* bloss  = (const float*)d_in[25];

    const int N  = in_sizes[0] / HF;
    const int E  = in_sizes[1] / 2;
    const int C_ = in_sizes[21];
    const int D_ = in_sizes[23];
    const int Gn = (out_size - 1) / (C_ + D_);

    const int* src = ei;
    const int* dst = ei + E;

    size_t NH = (size_t)N * HF;
    char* p = (char*)d_ws;
    unsigned short* xb = (unsigned short*)p; p += NH * 2;   // x bf16; becomes h1 after L1
    unsigned short* U  = (unsigned short*)p; p += NH * 2;
    unsigned short* T  = (unsigned short*)p; p += NH * 2;
    unsigned short* Hp = (unsigned short*)p; p += NH * 2;   // pre-BN output of each layer
    unsigned short* WtAll = (unsigned short*)p; p += 4 * 16384 * 2;
    float* S1    = (float*)p; p += HF * 4;
    float* S2    = (float*)p; p += HF * 4;
    float* scale = (float*)p; p += HF * 4;
    float* shift = (float*)p; p += HF * 4;
    float* z       = (float*)p; p += (size_t)Gn * HF * 4;
    float* partial = (float*)p; p += 1024 * 4;
    int* gstart = (int*)p; p += (Gn + 1) * 4;
    int* deg    = (int*)p; p += N * 4;          // reused as cursor
    int* off    = (int*)p; p += (N + 1) * 4;
    int* esrc   = (int*)p; p += E * 4;
    int* bsum   = (int*)p; p += 256 * 4;

    unsigned short* Wt1a = WtAll;
    unsigned short* Wt1b = WtAll + 16384;
    unsigned short* Wt2a = WtAll + 32768;
    unsigned short* Wt2b = WtAll + 49152;

    float* out1 = (float*)d_out;
    float* out3 = out1 + (size_t)Gn * C_;
    float* outm = out3 + (size_t)Gn * D_;

    int eBlocks    = (E + 255) / 256;
    int nBlocks    = (N + 255) / 256;
    int nb         = (N + 1023) / 1024;
    int castBlk    = ((int)(NH / 8) + 255) / 256;
    int gatherBlk  = (N * 16 + 255) / 256;
    int gemmBlocks = (N + 63) / 64;
    int applyBlk   = (N * 16 + 255) / 256;
    const int P    = 1024;
    float invN = 1.0f / (float)N;

    // ---- casts + CSR + graph bounds ----
    cast_x<<<castBlk, 256, 0, stream>>>(x, xb, (int)(NH / 8));
    cast_wt<<<4, 256, 0, stream>>>(W1a, W1b, W2a, W2b, WtAll);
    hipMemsetAsync(deg, 0, N * sizeof(int), stream);
    deg_count<<<eBlocks, 256, 0, stream>>>(dst, deg, E);
    scan_block_sums<<<nb, 256, 0, stream>>>(deg, bsum, N);
    scan_bsum<<<1, 64, 0, stream>>>(bsum, nb, off, N);
    scan_final<<<nb, 256, 0, stream>>>(deg, bsum, off, /*cursor=*/deg, N);
    fill_csr<<<eBlocks, 256, 0, stream>>>(src, dst, /*cursor=*/deg, esrc, E);
    graph_bounds<<<nBlocks, 256, 0, stream>>>(batch, gstart, N, Gn);

    // ---- layer 1 ----
    gather_u<<<gatherBlk, 256, 0, stream>>>(xb, off, esrc, eps1, U, N);
    gemm_mfma<<<gemmBlocks, 256, 0, stream>>>(U, Wt1a, b1a, T, N);
    gemm_mfma<<<gemmBlocks, 256, 0, stream>>>(T, Wt1b, b1b, Hp, N);
    hipMemsetAsync(S1, 0, 2 * HF * sizeof(float), stream);
    bn_stats<<<512, 128, 0, stream>>>(Hp, S1, S2, N);
    bn_finalize<<<1, 128, 0, stream>>>(S1, S2, g1, be1, scale, shift, invN);
    bn_apply<<<applyBlk, 256, 0, stream>>>(Hp, scale, shift, /*h1=*/xb, N * 16);

    // ---- layer 2 (BN2 folded into tail) ----
    gather_u<<<gatherBlk, 256, 0, stream>>>(xb, off, esrc, eps2, U, N);
    gemm_mfma<<<gemmBlocks, 256, 0, stream>>>(U, Wt2a, b2a, T, N);
    gemm_mfma<<<gemmBlocks, 256, 0, stream>>>(T, Wt2b, b2b, Hp, N);
    hipMemsetAsync(S1, 0, 2 * HF * sizeof(float), stream);
    bn_stats<<<512, 128, 0, stream>>>(Hp, S1, S2, N);
    bn_finalize<<<1, 128, 0, stream>>>(S1, S2, g2, be2, scale, shift, invN);

    // ---- tail ----
    pool_lin1<<<Gn, 128, 0, stream>>>(Hp, scale, shift, gstart, Wlin1, blin1, z);
    mse_partial<<<P, 256, 0, stream>>>(Hp, scale, shift, Wloss, bloss, degree, partial, N);
    mse_final<<<1, 256, 0, stream>>>(partial, outm, invN, P);
    heads<<<Gn, 64, 0, stream>>>(z, Wlin2, blin2, Wlin4, blin4, out1, out3, C_, D_);
}

// Round 5
// 688.353 us; speedup vs baseline: 10.7688x; 1.2155x over previous
//
#include <hip/hip_runtime.h>
#include <hip/hip_bf16.h>

#define HF 128   // feature/hidden dim (F == H == 128)
#define BSH 8    // bucket shift: 256 nodes per bucket
#define BSZ 256
#define NBMAX 1024
#define FCAP 8192

typedef __attribute__((ext_vector_type(8))) short bf16x8;
typedef __attribute__((ext_vector_type(4))) float f32x4;

__device__ inline float bflo(unsigned u) { return __uint_as_float(u << 16); }
__device__ inline float bfhi(unsigned u) { return __uint_as_float(u & 0xffff0000u); }
__device__ inline unsigned short f2bf(float f) {
    unsigned u = __float_as_uint(f);
    unsigned r = (u + 0x7fffu + ((u >> 16) & 1u)) >> 16;
    return (unsigned short)r;
}
__device__ inline unsigned pack2(float a, float b) {
    return (unsigned)f2bf(a) | ((unsigned)f2bf(b) << 16);
}

// ================= casts =================
__global__ __launch_bounds__(256) void cast_x(
    const float* __restrict__ x, unsigned short* __restrict__ xb, int nchunks)
{
    int i = blockIdx.x * 256 + threadIdx.x;
    if (i >= nchunks) return;
    float4 a = ((const float4*)x)[2 * i];
    float4 b = ((const float4*)x)[2 * i + 1];
    uint4 o;
    o.x = pack2(a.x, a.y); o.y = pack2(a.z, a.w);
    o.z = pack2(b.x, b.y); o.w = pack2(b.z, b.w);
    ((uint4*)xb)[i] = o;
}

__global__ void cast_wt(const float* __restrict__ w0, const float* __restrict__ w1,
                        const float* __restrict__ w2, const float* __restrict__ w3,
                        unsigned short* __restrict__ out)
{
    const float* W = (blockIdx.x == 0) ? w0 : (blockIdx.x == 1) ? w1
                   : (blockIdx.x == 2) ? w2 : w3;
    unsigned short* O = out + blockIdx.x * 16384;
    for (int idx = threadIdx.x; idx < 16384; idx += 256) {
        int n = idx >> 7, k = idx & 127;
        O[idx] = f2bf(W[k * 128 + n]);
    }
}

// ================= bucketed CSR build =================
// Pass A: per-bucket edge counts (LDS histogram, few global atomics)
__global__ __launch_bounds__(256) void bucket_hist(
    const int* __restrict__ dst, int* __restrict__ bcnt, int E, int NB, int chunk)
{
    __shared__ int lh[NBMAX];
    for (int i = threadIdx.x; i < NB; i += 256) lh[i] = 0;
    __syncthreads();
    int beg = blockIdx.x * chunk;
    int end = min(E, beg + chunk);
    for (int e = beg + threadIdx.x; e < end; e += 256)
        atomicAdd(&lh[dst[e] >> BSH], 1);
    __syncthreads();
    for (int i = threadIdx.x; i < NB; i += 256) {
        int c = lh[i];
        if (c) atomicAdd(&bcnt[i], c);
    }
}

// Pass B: exclusive scan of bucket counts -> boff[NB+1]; init bcur
__global__ void bucket_scan(const int* __restrict__ bcnt, int* __restrict__ boff,
                            int* __restrict__ bcur, int NB)
{
    __shared__ int part[256];
    int t = threadIdx.x;
    int v[4];
    int s = 0;
#pragma unroll
    for (int i = 0; i < 4; i++) {
        int idx = t * 4 + i;
        v[i] = (idx < NB) ? bcnt[idx] : 0;
        s += v[i];
    }
    part[t] = s;
    __syncthreads();
    for (int o = 1; o < 256; o <<= 1) {
        int y = (t >= o) ? part[t - o] : 0;
        __syncthreads();
        part[t] += y;
        __syncthreads();
    }
    int base = part[t] - s;  // exclusive base for this thread's 4 entries
#pragma unroll
    for (int i = 0; i < 4; i++) {
        int idx = t * 4 + i;
        if (idx < NB) {
            boff[idx] = base;
            bcur[idx] = base;
            base += v[i];
        }
    }
    if (t == 255) boff[NB] = part[255];
}

// Pass C: bin edges into bucket-contiguous ebuf, packed (src<<8)|(dst&255).
// Per-block LDS histogram + one global reservation per (block,bucket) =>
// contiguous per-bucket chunks, good write locality.
__global__ __launch_bounds__(256) void bucket_bin(
    const int* __restrict__ src, const int* __restrict__ dst,
    int* __restrict__ bcur, unsigned* __restrict__ ebuf, int E, int NB, int chunk)
{
    __shared__ int lh[NBMAX];
    for (int i = threadIdx.x; i < NB; i += 256) lh[i] = 0;
    __syncthreads();
    int beg = blockIdx.x * chunk;
    int end = min(E, beg + chunk);
    for (int e = beg + threadIdx.x; e < end; e += 256)
        atomicAdd(&lh[dst[e] >> BSH], 1);
    __syncthreads();
    for (int i = threadIdx.x; i < NB; i += 256) {
        int c = lh[i];
        lh[i] = c ? atomicAdd(&bcur[i], c) : 0;
    }
    __syncthreads();
    for (int e = beg + threadIdx.x; e < end; e += 256) {
        int d = dst[e];
        int b = d >> BSH;
        int pos = atomicAdd(&lh[b], 1);
        ebuf[pos] = ((unsigned)src[e] << BSH) | (unsigned)(d & (BSZ - 1));
    }
}

// Pass D: per-bucket fill — local degree histogram + scan emits off[] directly,
// LDS scatter, coalesced esrc write.
__global__ __launch_bounds__(256) void bucket_fill(
    const unsigned* __restrict__ ebuf, const int* __restrict__ boff,
    int* __restrict__ off, int* __restrict__ esrc, int N, int NB, int E)
{
    __shared__ int deg[BSZ];
    __shared__ int pref[BSZ];
    __shared__ int lcur[BSZ];
    __shared__ int lsr[FCAP];
    int b = blockIdx.x;
    int t = threadIdx.x;
    int segBeg = boff[b], segEnd = boff[b + 1];
    int segLen = segEnd - segBeg;
    int node0 = b << BSH;
    deg[t] = 0;
    __syncthreads();
    for (int i = segBeg + t; i < segEnd; i += 256)
        atomicAdd(&deg[ebuf[i] & (BSZ - 1)], 1);
    __syncthreads();
    int dv = deg[t];
    pref[t] = dv;
    __syncthreads();
    for (int o = 1; o < 256; o <<= 1) {
        int y = (t >= o) ? pref[t - o] : 0;
        __syncthreads();
        pref[t] += y;
        __syncthreads();
    }
    int excl = pref[t] - dv;
    int node = node0 + t;
    if (node < N) off[node] = segBeg + excl;
    lcur[t] = excl;
    if (b == NB - 1 && t == 0) off[N] = E;
    __syncthreads();
    if (segLen <= FCAP) {
        for (int i = segBeg + t; i < segEnd; i += 256) {
            unsigned v = ebuf[i];
            int slot = atomicAdd(&lcur[v & (BSZ - 1)], 1);
            lsr[slot] = (int)(v >> BSH);
        }
        __syncthreads();
        for (int i = t; i < segLen; i += 256) esrc[segBeg + i] = lsr[i];
    } else {  // fallback (never for uniform inputs): direct scatter within segment
        for (int i = segBeg + t; i < segEnd; i += 256) {
            unsigned v = ebuf[i];
            int slot = atomicAdd(&lcur[v & (BSZ - 1)], 1);
            esrc[segBeg + slot] = (int)(v >> BSH);
        }
    }
}

// ============ gather + fused U, bf16 in/out; optional BN1 affine fold ========
// FOLD=false: U = (1+eps)*x[node] + sum_nbr x
// FOLD=true : U = scale*((1+eps)*Hp[node] + sum_nbr Hp) + shift*((1+eps)+indeg)
template <bool FOLD>
__global__ __launch_bounds__(256) void gather_u(
    const unsigned short* __restrict__ xb, const int* __restrict__ off,
    const int* __restrict__ esrc, const float* __restrict__ epsp,
    const float* __restrict__ scale, const float* __restrict__ shift,
    unsigned short* __restrict__ Uo, int N)
{
    int lane16 = threadIdx.x & 15;
    int node = (blockIdx.x * 256 + threadIdx.x) >> 4;
    if (node >= N) return;
    int beg = off[node], end = off[node + 1];
    float acc[8] = {0.f, 0.f, 0.f, 0.f, 0.f, 0.f, 0.f, 0.f};
    for (int j0 = beg; j0 < end; j0 += 16) {
        int myidx = (j0 + lane16 < end) ? esrc[j0 + lane16] : 0;
        int cnt = min(16, end - j0);
        for (int t = 0; t < cnt; t++) {
            int s = __shfl(myidx, t, 16);
            uint4 p = *(const uint4*)(xb + (size_t)s * HF + lane16 * 8);
            acc[0] += bflo(p.x); acc[1] += bfhi(p.x);
            acc[2] += bflo(p.y); acc[3] += bfhi(p.y);
            acc[4] += bflo(p.z); acc[5] += bfhi(p.z);
            acc[6] += bflo(p.w); acc[7] += bfhi(p.w);
        }
    }
    float ep = 1.0f + epsp[0];
    uint4 xx = *(const uint4*)(xb + (size_t)node * HF + lane16 * 8);
    acc[0] += ep * bflo(xx.x); acc[1] += ep * bfhi(xx.x);
    acc[2] += ep * bflo(xx.y); acc[3] += ep * bfhi(xx.y);
    acc[4] += ep * bflo(xx.z); acc[5] += ep * bfhi(xx.z);
    acc[6] += ep * bflo(xx.w); acc[7] += ep * bfhi(xx.w);
    if (FOLD) {
        float cnt = ep + (float)(end - beg);
        const float4 s0 = *(const float4*)(scale + lane16 * 8);
        const float4 s1 = *(const float4*)(scale + lane16 * 8 + 4);
        const float4 h0 = *(const float4*)(shift + lane16 * 8);
        const float4 h1 = *(const float4*)(shift + lane16 * 8 + 4);
        acc[0] = acc[0] * s0.x + h0.x * cnt; acc[1] = acc[1] * s0.y + h0.y * cnt;
        acc[2] = acc[2] * s0.z + h0.z * cnt; acc[3] = acc[3] * s0.w + h0.w * cnt;
        acc[4] = acc[4] * s1.x + h1.x * cnt; acc[5] = acc[5] * s1.y + h1.y * cnt;
        acc[6] = acc[6] * s1.z + h1.z * cnt; acc[7] = acc[7] * s1.w + h1.w * cnt;
    }
    uint4 o;
    o.x = pack2(acc[0], acc[1]); o.y = pack2(acc[2], acc[3]);
    o.z = pack2(acc[4], acc[5]); o.w = pack2(acc[6], acc[7]);
    *(uint4*)(Uo + (size_t)node * HF + lane16 * 8) = o;
}

// ============ MFMA GEMM: out = relu(U @ W + bias), bf16 in/out, fp32 acc ====
#define AST 136
__global__ __launch_bounds__(256) void gemm_mfma(
    const unsigned short* __restrict__ U, const unsigned short* __restrict__ Wt,
    const float* __restrict__ bias, unsigned short* __restrict__ out, int n)
{
    __shared__ unsigned short lA[64 * AST];
    __shared__ unsigned short lB[128 * AST];
    int tid = threadIdx.x;
    int row0 = blockIdx.x * 64;

    for (int c = tid; c < 2048; c += 256) {
        int r = c >> 4, k16 = c & 15;
        uint4 v = *(const uint4*)(Wt + r * HF + k16 * 8);
        *(uint4*)(&lB[r * AST + k16 * 8]) = v;
    }
    for (int c = tid; c < 1024; c += 256) {
        int r = c >> 4, k16 = c & 15;
        int grow = row0 + r;
        uint4 v = make_uint4(0u, 0u, 0u, 0u);
        if (grow < n) v = *(const uint4*)(U + (size_t)grow * HF + k16 * 8);
        *(uint4*)(&lA[r * AST + k16 * 8]) = v;
    }
    __syncthreads();

    int w = tid >> 6;
    int lane = tid & 63;
    int m = lane & 15, quad = lane >> 4;
    int wr = w & 1;
    int wc = w >> 1;

    f32x4 acc[2][4];
#pragma unroll
    for (int i = 0; i < 2; i++)
#pragma unroll
        for (int j = 0; j < 4; j++) acc[i][j] = (f32x4){0.f, 0.f, 0.f, 0.f};

#pragma unroll
    for (int kk = 0; kk < 4; kk++) {
        int ko = kk * 32 + quad * 8;
        bf16x8 a0 = *(const bf16x8*)(&lA[(wr * 32 + m) * AST + ko]);
        bf16x8 a1 = *(const bf16x8*)(&lA[(wr * 32 + 16 + m) * AST + ko]);
#pragma unroll
        for (int nt = 0; nt < 4; nt++) {
            bf16x8 b = *(const bf16x8*)(&lB[(wc * 64 + nt * 16 + m) * AST + ko]);
            acc[0][nt] = __builtin_amdgcn_mfma_f32_16x16x32_bf16(a0, b, acc[0][nt], 0, 0, 0);
            acc[1][nt] = __builtin_amdgcn_mfma_f32_16x16x32_bf16(a1, b, acc[1][nt], 0, 0, 0);
        }
    }

#pragma unroll
    for (int nt = 0; nt < 4; nt++) {
        int col = wc * 64 + nt * 16 + m;
        float bv = bias[col];
#pragma unroll
        for (int mt = 0; mt < 2; mt++) {
#pragma unroll
            for (int r = 0; r < 4; r++) {
                int grow = row0 + wr * 32 + mt * 16 + quad * 4 + r;
                if (grow < n) {
                    float v = fmaxf(acc[mt][nt][r] + bv, 0.f);
                    out[(size_t)grow * HF + col] = f2bf(v);
                }
            }
        }
    }
}

// ---------------- BN column stats (bf16 input, fp32 accum)
__global__ void bn_stats(const unsigned short* __restrict__ h, float* __restrict__ S1,
                         float* __restrict__ S2, int n)
{
    int col = threadIdx.x;  // 128
    float s = 0.f, q = 0.f;
    for (int r = blockIdx.x; r < n; r += gridDim.x) {
        float v = __uint_as_float(((unsigned)h[(size_t)r * HF + col]) << 16);
        s += v;
        q += v * v;
    }
    atomicAdd(&S1[col], s);
    atomicAdd(&S2[col], q);
}

__global__ void bn_finalize(const float* __restrict__ S1, const float* __restrict__ S2,
                            const float* __restrict__ gamma, const float* __restrict__ beta,
                            float* __restrict__ scale, float* __restrict__ shift, float invN)
{
    int c = threadIdx.x;  // 128
    float mu = S1[c] * invN;
    float var = S2[c] * invN - mu * mu;
    float rs = rsqrtf(var + 1e-5f);
    float sc = gamma[c] * rs;
    scale[c] = sc;
    shift[c] = beta[c] - mu * sc;
}

// ---------------- graph segment bounds (batch sorted) ----------------
__global__ __launch_bounds__(256) void graph_bounds(
    const int* __restrict__ batch, int* __restrict__ gstart, int N, int Gn)
{
    int i = blockIdx.x * 256 + threadIdx.x;
    if (i >= N) return;
    int bi = batch[i];
    int bp = (i == 0) ? -1 : batch[i - 1];
    for (int g = bp + 1; g <= bi; g++) gstart[g] = i;
    if (i == N - 1) {
        for (int g = bi + 1; g <= Gn; g++) gstart[g] = N;
    }
}

// ---------------- pooled mean (BN2 folded) + z = relu(g @ Wlin1 + blin1)
__global__ void pool_lin1(const unsigned short* __restrict__ h2raw,
                          const float* __restrict__ scale, const float* __restrict__ shift,
                          const int* __restrict__ gstart, const float* __restrict__ W,
                          const float* __restrict__ bias, float* __restrict__ z)
{
    __shared__ float gv[HF];
    int gid = blockIdx.x;
    int c = threadIdx.x;  // 128
    int b = gstart[gid], e = gstart[gid + 1];
    float s = 0.f;
    for (int r = b; r < e; r++)
        s += __uint_as_float(((unsigned)h2raw[(size_t)r * HF + c]) << 16);
    float g = 0.f;
    if (e > b) g = scale[c] * (s / (float)(e - b)) + shift[c];
    gv[c] = g;
    __syncthreads();
    float a = bias[c];
#pragma unroll 8
    for (int k = 0; k < HF; k++) a += gv[k] * W[(size_t)k * HF + c];
    z[(size_t)gid * HF + c] = fmaxf(a, 0.f);
}

// ---------------- mse partials (BN2 folded into weights)
__global__ __launch_bounds__(256) void mse_partial(
    const unsigned short* __restrict__ h2raw, const float* __restrict__ scale,
    const float* __restrict__ shift, const float* __restrict__ Wloss,
    const float* __restrict__ blossp, const float* __restrict__ degree,
    float* __restrict__ partial, int N)
{
    __shared__ float red[4];
    int lane = threadIdx.x & 63;
    int wv = threadIdx.x >> 6;
    float wl0 = scale[lane] * Wloss[lane];
    float wl1 = scale[lane + 64] * Wloss[lane + 64];
    float c0l = shift[lane] * Wloss[lane] + shift[lane + 64] * Wloss[lane + 64];
    float bl = blossp[0];
    float acc = 0.f;
    for (int node = blockIdx.x * 4 + wv; node < N; node += gridDim.x * 4) {
        const unsigned short* row = h2raw + (size_t)node * HF;
        float v0 = __uint_as_float(((unsigned)row[lane]) << 16);
        float v1 = __uint_as_float(((unsigned)row[lane + 64]) << 16);
        float m = v0 * wl0 + v1 * wl1 + c0l;
#pragma unroll
        for (int off = 32; off > 0; off >>= 1) m += __shfl_down(m, off);
        if (lane == 0) {
            float d = m + bl - degree[node];
            acc += d * d;
        }
    }
    if (lane == 0) red[wv] = acc;
    __syncthreads();
    if (threadIdx.x == 0)
        partial[blockIdx.x] = red[0] + red[1] + red[2] + red[3];
}

__global__ void mse_final(const float* __restrict__ partial, float* __restrict__ out,
                          float invN, int P)
{
    __shared__ float sd[256];
    int t = threadIdx.x;
    float s = 0.f;
    for (int i = t; i < P; i += 256) s += partial[i];
    sd[t] = s;
    __syncthreads();
    for (int o = 128; o > 0; o >>= 1) {
        if (t < o) sd[t] += sd[t + o];
        __syncthreads();
    }
    if (t == 0) out[0] = sd[0] * invN;
}

// ---------------- heads
__global__ void heads(const float* __restrict__ z, const float* __restrict__ W2,
                      const float* __restrict__ b2, const float* __restrict__ W4,
                      const float* __restrict__ b4, float* __restrict__ out1,
                      float* __restrict__ out3, int C_, int D_)
{
    __shared__ float zr[HF];
    __shared__ float logits[16];
    __shared__ float lse_s;
    int gid = blockIdx.x;
    int t = threadIdx.x;  // 64
    zr[t] = z[(size_t)gid * HF + t];
    zr[t + 64] = z[(size_t)gid * HF + t + 64];
    __syncthreads();
    if (t < C_) {
        float a = b2[t];
        for (int k = 0; k < HF; k++) a += zr[k] * W2[(size_t)k * C_ + t];
        logits[t] = a;
    }
    __syncthreads();
    if (t == 0) {
        float mx = -1e30f;
        for (int i = 0; i < C_; i++) mx = fmaxf(mx, logits[i]);
        float s = 0.f;
        for (int i = 0; i < C_; i++) s += expf(logits[i] - mx);
        lse_s = mx + logf(s);
    }
    __syncthreads();
    if (t < C_) out1[(size_t)gid * C_ + t] = logits[t] - lse_s;
    if (t < D_) {
        float a = b4[t];
        for (int k = 0; k < HF; k++) a += zr[k] * W4[(size_t)k * D_ + t];
        out3[(size_t)gid * D_ + t] = a;
    }
}

extern "C" void kernel_launch(void* const* d_in, const int* in_sizes, int n_in,
                              void* d_out, int out_size, void* d_ws, size_t ws_size,
                              hipStream_t stream)
{
    const float* x      = (const float*)d_in[0];
    const int*   ei     = (const int*)d_in[1];
    const int*   batch  = (const int*)d_in[2];
    const float* degree = (const float*)d_in[3];
    const float* eps1   = (const float*)d_in[4];
    const float* W1a    = (const float*)d_in[5];
    const float* b1a    = (const float*)d_in[6];
    const float* W1b    = (const float*)d_in[7];
    const float* b1b    = (const float*)d_in[8];
    const float* g1     = (const float*)d_in[9];
    const float* be1    = (const float*)d_in[10];
    const float* eps2   = (const float*)d_in[11];
    const float* W2a    = (const float*)d_in[12];
    const float* b2a    = (const float*)d_in[13];
    const float* W2b    = (const float*)d_in[14];
    const float* b2b    = (const float*)d_in[15];
    const float* g2     = (const float*)d_in[16];
    const float* be2    = (const float*)d_in[17];
    const float* Wlin1  = (const float*)d_in[18];
    const float* blin1  = (const float*)d_in[19];
    const float* Wlin2  = (const float*)d_in[20];
    const float* blin2  = (const float*)d_in[21];
    const float* Wlin4  = (const float*)d_in[22];
    const float* blin4  = (const float*)d_in[23];
    const float* Wloss  = (const float*)d_in[24];
    const float* bloss  = (const float*)d_in[25];

    const int N  = in_sizes[0] / HF;
    const int E  = in_sizes[1] / 2;
    const int C_ = in_sizes[21];
    const int D_ = in_sizes[23];
    const int Gn = (out_size - 1) / (C_ + D_);
    const int NB = (N + BSZ - 1) >> BSH;

    const int* src = ei;
    const int* dst = ei + E;

    size_t NH = (size_t)N * HF;
    char* p = (char*)d_ws;
    unsigned short* xb = (unsigned short*)p; p += NH * 2;
    unsigned short* U  = (unsigned short*)p; p += NH * 2;
    unsigned short* T  = (unsigned short*)p; p += NH * 2;
    unsigned short* Hp = (unsigned short*)p; p += NH * 2;
    unsigned short* WtAll = (unsigned short*)p; p += 4 * 16384 * 2;
    float* S1    = (float*)p; p += HF * 4;
    float* S2    = (float*)p; p += HF * 4;
    float* scale = (float*)p; p += HF * 4;
    float* shift = (float*)p; p += HF * 4;
    float* z       = (float*)p; p += (size_t)Gn * HF * 4;
    float* partial = (float*)p; p += 1024 * 4;
    int* gstart = (int*)p; p += (Gn + 1) * 4;
    int* bcnt   = (int*)p; p += NBMAX * 4;
    int* boff   = (int*)p; p += (NBMAX + 1) * 4;
    int* bcur   = (int*)p; p += NBMAX * 4;
    int* off    = (int*)p; p += (N + 1) * 4;
    int* esrc   = (int*)p; p += E * 4;
    unsigned* ebuf = (unsigned*)p; p += E * 4;

    unsigned short* Wt1a = WtAll;
    unsigned short* Wt1b = WtAll + 16384;
    unsigned short* Wt2a = WtAll + 32768;
    unsigned short* Wt2b = WtAll + 49152;

    float* out1 = (float*)d_out;
    float* out3 = out1 + (size_t)Gn * C_;
    float* outm = out3 + (size_t)Gn * D_;

    int nBlocks   = (N + 255) / 256;
    int castBlk   = ((int)(NH / 8) + 255) / 256;
    int gatherBlk = (N * 16 + 255) / 256;
    int gemmBlk   = (N + 63) / 64;
    const int BINB = 512;
    int chunk = (E + BINB - 1) / BINB;
    const int P = 1024;
    float invN = 1.0f / (float)N;

    // ---- casts ----
    cast_x<<<castBlk, 256, 0, stream>>>(x, xb, (int)(NH / 8));
    cast_wt<<<4, 256, 0, stream>>>(W1a, W1b, W2a, W2b, WtAll);

    // ---- bucketed CSR build ----
    hipMemsetAsync(bcnt, 0, NB * sizeof(int), stream);
    bucket_hist<<<BINB, 256, 0, stream>>>(dst, bcnt, E, NB, chunk);
    bucket_scan<<<1, 256, 0, stream>>>(bcnt, boff, bcur, NB);
    bucket_bin<<<BINB, 256, 0, stream>>>(src, dst, bcur, ebuf, E, NB, chunk);
    bucket_fill<<<NB, 256, 0, stream>>>(ebuf, boff, off, esrc, N, NB, E);
    graph_bounds<<<nBlocks, 256, 0, stream>>>(batch, gstart, N, Gn);

    // ---- layer 1 ----
    gather_u<false><<<gatherBlk, 256, 0, stream>>>(xb, off, esrc, eps1, nullptr, nullptr, U, N);
    gemm_mfma<<<gemmBlk, 256, 0, stream>>>(U, Wt1a, b1a, T, N);
    gemm_mfma<<<gemmBlk, 256, 0, stream>>>(T, Wt1b, b1b, Hp, N);
    hipMemsetAsync(S1, 0, 2 * HF * sizeof(float), stream);
    bn_stats<<<512, 128, 0, stream>>>(Hp, S1, S2, N);
    bn_finalize<<<1, 128, 0, stream>>>(S1, S2, g1, be1, scale, shift, invN);

    // ---- layer 2 (BN1 folded into gather; BN2 folded into tail) ----
    gather_u<true><<<gatherBlk, 256, 0, stream>>>(Hp, off, esrc, eps2, scale, shift, U, N);
    gemm_mfma<<<gemmBlk, 256, 0, stream>>>(U, Wt2a, b2a, T, N);
    gemm_mfma<<<gemmBlk, 256, 0, stream>>>(T, Wt2b, b2b, Hp, N);
    hipMemsetAsync(S1, 0, 2 * HF * sizeof(float), stream);
    bn_stats<<<512, 128, 0, stream>>>(Hp, S1, S2, N);
    bn_finalize<<<1, 128, 0, stream>>>(S1, S2, g2, be2, scale, shift, invN);

    // ---- tail ----
    pool_lin1<<<Gn, 128, 0, stream>>>(Hp, scale, shift, gstart, Wlin1, blin1, z);
    mse_partial<<<P, 256, 0, stream>>>(Hp, scale, shift, Wloss, bloss, degree, partial, N);
    mse_final<<<1, 256, 0, stream>>>(partial, outm, invN, P);
    heads<<<Gn, 64, 0, stream>>>(z, Wlin2, blin2, Wlin4, blin4, out1, out3, C_, D_);
}

// Round 6
// 539.513 us; speedup vs baseline: 13.7397x; 1.2759x over previous
//
#include <hip/hip_runtime.h>
#include <hip/hip_bf16.h>

#define HF 128   // feature/hidden dim (F == H == 128)
#define BSH 8    // bucket shift: 256 nodes per bucket
#define BSZ 256
#define NBMAX 1024
#define FCAP 8192

typedef __attribute__((ext_vector_type(8))) short bf16x8;
typedef __attribute__((ext_vector_type(4))) float f32x4;

__device__ inline float bflo(unsigned u) { return __uint_as_float(u << 16); }
__device__ inline float bfhi(unsigned u) { return __uint_as_float(u & 0xffff0000u); }
__device__ inline unsigned short f2bf(float f) {
    unsigned u = __float_as_uint(f);
    unsigned r = (u + 0x7fffu + ((u >> 16) & 1u)) >> 16;
    return (unsigned short)r;
}
__device__ inline unsigned pack2(float a, float b) {
    return (unsigned)f2bf(a) | ((unsigned)f2bf(b) << 16);
}

// ================= casts =================
__global__ __launch_bounds__(256) void cast_x(
    const float* __restrict__ x, unsigned short* __restrict__ xb, int nchunks)
{
    int i = blockIdx.x * 256 + threadIdx.x;
    if (i >= nchunks) return;
    float4 a = ((const float4*)x)[2 * i];
    float4 b = ((const float4*)x)[2 * i + 1];
    uint4 o;
    o.x = pack2(a.x, a.y); o.y = pack2(a.z, a.w);
    o.z = pack2(b.x, b.y); o.w = pack2(b.z, b.w);
    ((uint4*)xb)[i] = o;
}

__global__ void cast_wt(const float* __restrict__ w0, const float* __restrict__ w1,
                        const float* __restrict__ w2, const float* __restrict__ w3,
                        unsigned short* __restrict__ out)
{
    const float* W = (blockIdx.x == 0) ? w0 : (blockIdx.x == 1) ? w1
                   : (blockIdx.x == 2) ? w2 : w3;
    unsigned short* O = out + blockIdx.x * 16384;
    for (int idx = threadIdx.x; idx < 16384; idx += 256) {
        int n = idx >> 7, k = idx & 127;
        O[idx] = f2bf(W[k * 128 + n]);
    }
}

// ================= bucketed CSR build =================
__global__ __launch_bounds__(256) void bucket_hist(
    const int* __restrict__ dst, int* __restrict__ bcnt, int E, int NB, int chunk)
{
    __shared__ int lh[NBMAX];
    for (int i = threadIdx.x; i < NB; i += 256) lh[i] = 0;
    __syncthreads();
    int beg = blockIdx.x * chunk;
    int end = min(E, beg + chunk);
    for (int e = beg + threadIdx.x; e < end; e += 256)
        atomicAdd(&lh[dst[e] >> BSH], 1);
    __syncthreads();
    for (int i = threadIdx.x; i < NB; i += 256) {
        int c = lh[i];
        if (c) atomicAdd(&bcnt[i], c);
    }
}

__global__ void bucket_scan(const int* __restrict__ bcnt, int* __restrict__ boff,
                            int* __restrict__ bcur, int NB)
{
    __shared__ int part[256];
    int t = threadIdx.x;
    int v[4];
    int s = 0;
#pragma unroll
    for (int i = 0; i < 4; i++) {
        int idx = t * 4 + i;
        v[i] = (idx < NB) ? bcnt[idx] : 0;
        s += v[i];
    }
    part[t] = s;
    __syncthreads();
    for (int o = 1; o < 256; o <<= 1) {
        int y = (t >= o) ? part[t - o] : 0;
        __syncthreads();
        part[t] += y;
        __syncthreads();
    }
    int base = part[t] - s;
#pragma unroll
    for (int i = 0; i < 4; i++) {
        int idx = t * 4 + i;
        if (idx < NB) {
            boff[idx] = base;
            bcur[idx] = base;
            base += v[i];
        }
    }
    if (t == 255) boff[NB] = part[255];
}

__global__ __launch_bounds__(256) void bucket_bin(
    const int* __restrict__ src, const int* __restrict__ dst,
    int* __restrict__ bcur, unsigned* __restrict__ ebuf, int E, int NB, int chunk)
{
    __shared__ int lh[NBMAX];
    for (int i = threadIdx.x; i < NB; i += 256) lh[i] = 0;
    __syncthreads();
    int beg = blockIdx.x * chunk;
    int end = min(E, beg + chunk);
    for (int e = beg + threadIdx.x; e < end; e += 256)
        atomicAdd(&lh[dst[e] >> BSH], 1);
    __syncthreads();
    for (int i = threadIdx.x; i < NB; i += 256) {
        int c = lh[i];
        lh[i] = c ? atomicAdd(&bcur[i], c) : 0;
    }
    __syncthreads();
    for (int e = beg + threadIdx.x; e < end; e += 256) {
        int d = dst[e];
        int b = d >> BSH;
        int pos = atomicAdd(&lh[b], 1);
        ebuf[pos] = ((unsigned)src[e] << BSH) | (unsigned)(d & (BSZ - 1));
    }
}

__global__ __launch_bounds__(256) void bucket_fill(
    const unsigned* __restrict__ ebuf, const int* __restrict__ boff,
    int* __restrict__ off, int* __restrict__ esrc, int N, int NB, int E)
{
    __shared__ int deg[BSZ];
    __shared__ int pref[BSZ];
    __shared__ int lcur[BSZ];
    __shared__ int lsr[FCAP];
    int b = blockIdx.x;
    int t = threadIdx.x;
    int segBeg = boff[b], segEnd = boff[b + 1];
    int segLen = segEnd - segBeg;
    int node0 = b << BSH;
    deg[t] = 0;
    __syncthreads();
    for (int i = segBeg + t; i < segEnd; i += 256)
        atomicAdd(&deg[ebuf[i] & (BSZ - 1)], 1);
    __syncthreads();
    int dv = deg[t];
    pref[t] = dv;
    __syncthreads();
    for (int o = 1; o < 256; o <<= 1) {
        int y = (t >= o) ? pref[t - o] : 0;
        __syncthreads();
        pref[t] += y;
        __syncthreads();
    }
    int excl = pref[t] - dv;
    int node = node0 + t;
    if (node < N) off[node] = segBeg + excl;
    lcur[t] = excl;
    if (b == NB - 1 && t == 0) off[N] = E;
    __syncthreads();
    if (segLen <= FCAP) {
        for (int i = segBeg + t; i < segEnd; i += 256) {
            unsigned v = ebuf[i];
            int slot = atomicAdd(&lcur[v & (BSZ - 1)], 1);
            lsr[slot] = (int)(v >> BSH);
        }
        __syncthreads();
        for (int i = t; i < segLen; i += 256) esrc[segBeg + i] = lsr[i];
    } else {
        for (int i = segBeg + t; i < segEnd; i += 256) {
            unsigned v = ebuf[i];
            int slot = atomicAdd(&lcur[v & (BSZ - 1)], 1);
            esrc[segBeg + slot] = (int)(v >> BSH);
        }
    }
}

// ============ gather + fused U, bf16 in/out; optional BN1 affine fold ========
template <bool FOLD>
__global__ __launch_bounds__(256) void gather_u(
    const unsigned short* __restrict__ xb, const int* __restrict__ off,
    const int* __restrict__ esrc, const float* __restrict__ epsp,
    const float* __restrict__ scale, const float* __restrict__ shift,
    unsigned short* __restrict__ Uo, int N)
{
    int lane16 = threadIdx.x & 15;
    int node = (blockIdx.x * 256 + threadIdx.x) >> 4;
    if (node >= N) return;
    int beg = off[node], end = off[node + 1];
    float acc[8] = {0.f, 0.f, 0.f, 0.f, 0.f, 0.f, 0.f, 0.f};
    for (int j0 = beg; j0 < end; j0 += 16) {
        int myidx = (j0 + lane16 < end) ? esrc[j0 + lane16] : 0;
        int cnt = min(16, end - j0);
        for (int t = 0; t < cnt; t++) {
            int s = __shfl(myidx, t, 16);
            uint4 p = *(const uint4*)(xb + (size_t)s * HF + lane16 * 8);
            acc[0] += bflo(p.x); acc[1] += bfhi(p.x);
            acc[2] += bflo(p.y); acc[3] += bfhi(p.y);
            acc[4] += bflo(p.z); acc[5] += bfhi(p.z);
            acc[6] += bflo(p.w); acc[7] += bfhi(p.w);
        }
    }
    float ep = 1.0f + epsp[0];
    uint4 xx = *(const uint4*)(xb + (size_t)node * HF + lane16 * 8);
    acc[0] += ep * bflo(xx.x); acc[1] += ep * bfhi(xx.x);
    acc[2] += ep * bflo(xx.y); acc[3] += ep * bfhi(xx.y);
    acc[4] += ep * bflo(xx.z); acc[5] += ep * bfhi(xx.z);
    acc[6] += ep * bflo(xx.w); acc[7] += ep * bfhi(xx.w);
    if (FOLD) {
        float cnt = ep + (float)(end - beg);
        const float4 s0 = *(const float4*)(scale + lane16 * 8);
        const float4 s1 = *(const float4*)(scale + lane16 * 8 + 4);
        const float4 h0 = *(const float4*)(shift + lane16 * 8);
        const float4 h1 = *(const float4*)(shift + lane16 * 8 + 4);
        acc[0] = acc[0] * s0.x + h0.x * cnt; acc[1] = acc[1] * s0.y + h0.y * cnt;
        acc[2] = acc[2] * s0.z + h0.z * cnt; acc[3] = acc[3] * s0.w + h0.w * cnt;
        acc[4] = acc[4] * s1.x + h1.x * cnt; acc[5] = acc[5] * s1.y + h1.y * cnt;
        acc[6] = acc[6] * s1.z + h1.z * cnt; acc[7] = acc[7] * s1.w + h1.w * cnt;
    }
    uint4 o;
    o.x = pack2(acc[0], acc[1]); o.y = pack2(acc[2], acc[3]);
    o.z = pack2(acc[4], acc[5]); o.w = pack2(acc[6], acc[7]);
    *(uint4*)(Uo + (size_t)node * HF + lane16 * 8) = o;
}

// ====== fused double-GEMM + BN stats epilogue ======
// Hp = relu(relu(U@Wa+ba)@Wb+bb); S1/S2 += column sums / sumsq of Hp.
// T stays in LDS (lA is overwritten after stage 1); Wb overwrites Wa in lB.
#define AST 136
__global__ __launch_bounds__(256) void gemm2_mfma(
    const unsigned short* __restrict__ U,
    const unsigned short* __restrict__ Wta, const float* __restrict__ ba,
    const unsigned short* __restrict__ Wtb, const float* __restrict__ bb,
    unsigned short* __restrict__ out, float* __restrict__ S1, float* __restrict__ S2,
    int n)
{
    __shared__ unsigned short lA[64 * AST];
    __shared__ unsigned short lB[128 * AST];
    __shared__ float lS1[HF], lS2[HF];
    int tid = threadIdx.x;
    int row0 = blockIdx.x * 64;

    if (tid < HF) { lS1[tid] = 0.f; lS2[tid] = 0.f; }
    for (int c = tid; c < 2048; c += 256) {          // Wa -> lB
        int r = c >> 4, k16 = c & 15;
        *(uint4*)(&lB[r * AST + k16 * 8]) = *(const uint4*)(Wta + r * HF + k16 * 8);
    }
    for (int c = tid; c < 1024; c += 256) {          // U tile -> lA
        int r = c >> 4, k16 = c & 15;
        int grow = row0 + r;
        uint4 v = make_uint4(0u, 0u, 0u, 0u);
        if (grow < n) v = *(const uint4*)(U + (size_t)grow * HF + k16 * 8);
        *(uint4*)(&lA[r * AST + k16 * 8]) = v;
    }
    __syncthreads();

    int w = tid >> 6;
    int lane = tid & 63;
    int m = lane & 15, quad = lane >> 4;
    int wr = w & 1;
    int wc = w >> 1;

    f32x4 acc[2][4];
#pragma unroll
    for (int i = 0; i < 2; i++)
#pragma unroll
        for (int j = 0; j < 4; j++) acc[i][j] = (f32x4){0.f, 0.f, 0.f, 0.f};

#pragma unroll
    for (int kk = 0; kk < 4; kk++) {
        int ko = kk * 32 + quad * 8;
        bf16x8 a0 = *(const bf16x8*)(&lA[(wr * 32 + m) * AST + ko]);
        bf16x8 a1 = *(const bf16x8*)(&lA[(wr * 32 + 16 + m) * AST + ko]);
#pragma unroll
        for (int nt = 0; nt < 4; nt++) {
            bf16x8 b = *(const bf16x8*)(&lB[(wc * 64 + nt * 16 + m) * AST + ko]);
            acc[0][nt] = __builtin_amdgcn_mfma_f32_16x16x32_bf16(a0, b, acc[0][nt], 0, 0, 0);
            acc[1][nt] = __builtin_amdgcn_mfma_f32_16x16x32_bf16(a1, b, acc[1][nt], 0, 0, 0);
        }
    }
    __syncthreads();   // everyone done reading lA (U) and lB (Wa)

    // T tile -> lA (relu(acc+ba), bf16); Wb -> lB
#pragma unroll
    for (int nt = 0; nt < 4; nt++) {
        int col = wc * 64 + nt * 16 + m;
        float bav = ba[col];
#pragma unroll
        for (int mt = 0; mt < 2; mt++) {
#pragma unroll
            for (int r = 0; r < 4; r++) {
                int lrow = wr * 32 + mt * 16 + quad * 4 + r;
                float v = fmaxf(acc[mt][nt][r] + bav, 0.f);
                lA[lrow * AST + col] = f2bf(v);
            }
        }
    }
    for (int c = tid; c < 2048; c += 256) {
        int r = c >> 4, k16 = c & 15;
        *(uint4*)(&lB[r * AST + k16 * 8]) = *(const uint4*)(Wtb + r * HF + k16 * 8);
    }
    __syncthreads();

#pragma unroll
    for (int i = 0; i < 2; i++)
#pragma unroll
        for (int j = 0; j < 4; j++) acc[i][j] = (f32x4){0.f, 0.f, 0.f, 0.f};

#pragma unroll
    for (int kk = 0; kk < 4; kk++) {
        int ko = kk * 32 + quad * 8;
        bf16x8 a0 = *(const bf16x8*)(&lA[(wr * 32 + m) * AST + ko]);
        bf16x8 a1 = *(const bf16x8*)(&lA[(wr * 32 + 16 + m) * AST + ko]);
#pragma unroll
        for (int nt = 0; nt < 4; nt++) {
            bf16x8 b = *(const bf16x8*)(&lB[(wc * 64 + nt * 16 + m) * AST + ko]);
            acc[0][nt] = __builtin_amdgcn_mfma_f32_16x16x32_bf16(a0, b, acc[0][nt], 0, 0, 0);
            acc[1][nt] = __builtin_amdgcn_mfma_f32_16x16x32_bf16(a1, b, acc[1][nt], 0, 0, 0);
        }
    }

    // epilogue: relu + store + column stats
#pragma unroll
    for (int nt = 0; nt < 4; nt++) {
        int col = wc * 64 + nt * 16 + m;
        float bbv = bb[col];
        float cs = 0.f, cq = 0.f;
#pragma unroll
        for (int mt = 0; mt < 2; mt++) {
#pragma unroll
            for (int r = 0; r < 4; r++) {
                int grow = row0 + wr * 32 + mt * 16 + quad * 4 + r;
                float v = fmaxf(acc[mt][nt][r] + bbv, 0.f);
                if (grow < n) {
                    out[(size_t)grow * HF + col] = f2bf(v);
                    cs += v;
                    cq += v * v;
                }
            }
        }
        cs += __shfl_down(cs, 32); cs += __shfl_down(cs, 16);
        cq += __shfl_down(cq, 32); cq += __shfl_down(cq, 16);
        if (quad == 0) {
            atomicAdd(&lS1[col], cs);
            atomicAdd(&lS2[col], cq);
        }
    }
    __syncthreads();
    if (tid < HF) {
        atomicAdd(&S1[tid], lS1[tid]);
        atomicAdd(&S2[tid], lS2[tid]);
    }
}

__global__ void bn_finalize(const float* __restrict__ S1, const float* __restrict__ S2,
                            const float* __restrict__ gamma, const float* __restrict__ beta,
                            float* __restrict__ scale, float* __restrict__ shift, float invN)
{
    int c = threadIdx.x;  // 128
    float mu = S1[c] * invN;
    float var = S2[c] * invN - mu * mu;
    float rs = rsqrtf(var + 1e-5f);
    float sc = gamma[c] * rs;
    scale[c] = sc;
    shift[c] = beta[c] - mu * sc;
}

// ---------------- graph segment bounds (batch sorted) ----------------
__global__ __launch_bounds__(256) void graph_bounds(
    const int* __restrict__ batch, int* __restrict__ gstart, int N, int Gn)
{
    int i = blockIdx.x * 256 + threadIdx.x;
    if (i >= N) return;
    int bi = batch[i];
    int bp = (i == 0) ? -1 : batch[i - 1];
    for (int g = bp + 1; g <= bi; g++) gstart[g] = i;
    if (i == N - 1) {
        for (int g = bi + 1; g <= Gn; g++) gstart[g] = N;
    }
}

// ---------------- pooled mean (BN2 folded) + z = relu(g @ Wlin1 + blin1)
// 512 threads: 8 row-groups x 64 col-pairs; LDS tree for pool and lin1.
__global__ __launch_bounds__(512) void pool_lin1(
    const unsigned short* __restrict__ h2raw,
    const float* __restrict__ scale, const float* __restrict__ shift,
    const int* __restrict__ gstart, const float* __restrict__ W,
    const float* __restrict__ bias, float* __restrict__ z)
{
    __shared__ float red[8][HF];
    __shared__ float gv[HF];
    __shared__ float part[4][HF];
    int gid = blockIdx.x;
    int t = threadIdx.x;
    int c2 = t & 63;     // column pair
    int rg = t >> 6;     // row group 0..7
    int b = gstart[gid], e = gstart[gid + 1];
    float s0 = 0.f, s1 = 0.f;
    for (int r = b + rg; r < e; r += 8) {
        unsigned u = *(const unsigned*)(h2raw + (size_t)r * HF + c2 * 2);
        s0 += bflo(u);
        s1 += bfhi(u);
    }
    red[rg][c2 * 2] = s0;
    red[rg][c2 * 2 + 1] = s1;
    __syncthreads();
    if (t < HF) {
        float s = red[0][t] + red[1][t] + red[2][t] + red[3][t]
                + red[4][t] + red[5][t] + red[6][t] + red[7][t];
        gv[t] = (e > b) ? scale[t] * (s / (float)(e - b)) + shift[t] : 0.f;
    }
    __syncthreads();
    int c = t & 127, kg = t >> 7;  // 4 k-groups of 32
    float a = 0.f;
#pragma unroll 8
    for (int k = kg * 32; k < kg * 32 + 32; k++) a += gv[k] * W[(size_t)k * HF + c];
    part[kg][c] = a;
    __syncthreads();
    if (t < HF) {
        float aa = part[0][t] + part[1][t] + part[2][t] + part[3][t] + bias[t];
        z[(size_t)gid * HF + t] = fmaxf(aa, 0.f);
    }
}

// ---------------- mse partials (BN2 folded into weights)
__global__ __launch_bounds__(256) void mse_partial(
    const unsigned short* __restrict__ h2raw, const float* __restrict__ scale,
    const float* __restrict__ shift, const float* __restrict__ Wloss,
    const float* __restrict__ blossp, const float* __restrict__ degree,
    float* __restrict__ partial, int N)
{
    __shared__ float red[4];
    int lane = threadIdx.x & 63;
    int wv = threadIdx.x >> 6;
    float wla = scale[2 * lane] * Wloss[2 * lane];
    float wlb = scale[2 * lane + 1] * Wloss[2 * lane + 1];
    float c0l = shift[2 * lane] * Wloss[2 * lane] + shift[2 * lane + 1] * Wloss[2 * lane + 1];
    float bl = blossp[0];
    float acc = 0.f;
    for (int node = blockIdx.x * 4 + wv; node < N; node += gridDim.x * 4) {
        unsigned u = *(const unsigned*)(h2raw + (size_t)node * HF + 2 * lane);
        float m = bflo(u) * wla + bfhi(u) * wlb + c0l;
#pragma unroll
        for (int off = 32; off > 0; off >>= 1) m += __shfl_down(m, off);
        if (lane == 0) {
            float d = m + bl - degree[node];
            acc += d * d;
        }
    }
    if (lane == 0) red[wv] = acc;
    __syncthreads();
    if (threadIdx.x == 0)
        partial[blockIdx.x] = red[0] + red[1] + red[2] + red[3];
}

__global__ void mse_final(const float* __restrict__ partial, float* __restrict__ out,
                          float invN, int P)
{
    __shared__ float sd[256];
    int t = threadIdx.x;
    float s = 0.f;
    for (int i = t; i < P; i += 256) s += partial[i];
    sd[t] = s;
    __syncthreads();
    for (int o = 128; o > 0; o >>= 1) {
        if (t < o) sd[t] += sd[t + o];
        __syncthreads();
    }
    if (t == 0) out[0] = sd[0] * invN;
}

// ---------------- heads
__global__ void heads(const float* __restrict__ z, const float* __restrict__ W2,
                      const float* __restrict__ b2, const float* __restrict__ W4,
                      const float* __restrict__ b4, float* __restrict__ out1,
                      float* __restrict__ out3, int C_, int D_)
{
    __shared__ float zr[HF];
    __shared__ float logits[16];
    __shared__ float lse_s;
    int gid = blockIdx.x;
    int t = threadIdx.x;  // 64
    zr[t] = z[(size_t)gid * HF + t];
    zr[t + 64] = z[(size_t)gid * HF + t + 64];
    __syncthreads();
    if (t < C_) {
        float a = b2[t];
        for (int k = 0; k < HF; k++) a += zr[k] * W2[(size_t)k * C_ + t];
        logits[t] = a;
    }
    __syncthreads();
    if (t == 0) {
        float mx = -1e30f;
        for (int i = 0; i < C_; i++) mx = fmaxf(mx, logits[i]);
        float s = 0.f;
        for (int i = 0; i < C_; i++) s += expf(logits[i] - mx);
        lse_s = mx + logf(s);
    }
    __syncthreads();
    if (t < C_) out1[(size_t)gid * C_ + t] = logits[t] - lse_s;
    if (t < D_) {
        float a = b4[t];
        for (int k = 0; k < HF; k++) a += zr[k] * W4[(size_t)k * D_ + t];
        out3[(size_t)gid * D_ + t] = a;
    }
}

extern "C" void kernel_launch(void* const* d_in, const int* in_sizes, int n_in,
                              void* d_out, int out_size, void* d_ws, size_t ws_size,
                              hipStream_t stream)
{
    const float* x      = (const float*)d_in[0];
    const int*   ei     = (const int*)d_in[1];
    const int*   batch  = (const int*)d_in[2];
    const float* degree = (const float*)d_in[3];
    const float* eps1   = (const float*)d_in[4];
    const float* W1a    = (const float*)d_in[5];
    const float* b1a    = (const float*)d_in[6];
    const float* W1b    = (const float*)d_in[7];
    const float* b1b    = (const float*)d_in[8];
    const float* g1     = (const float*)d_in[9];
    const float* be1    = (const float*)d_in[10];
    const float* eps2   = (const float*)d_in[11];
    const float* W2a    = (const float*)d_in[12];
    const float* b2a    = (const float*)d_in[13];
    const float* W2b    = (const float*)d_in[14];
    const float* b2b    = (const float*)d_in[15];
    const float* g2     = (const float*)d_in[16];
    const float* be2    = (const float*)d_in[17];
    const float* Wlin1  = (const float*)d_in[18];
    const float* blin1  = (const float*)d_in[19];
    const float* Wlin2  = (const float*)d_in[20];
    const float* blin2  = (const float*)d_in[21];
    const float* Wlin4  = (const float*)d_in[22];
    const float* blin4  = (const float*)d_in[23];
    const float* Wloss  = (const float*)d_in[24];
    const float* bloss  = (const float*)d_in[25];

    const int N  = in_sizes[0] / HF;
    const int E  = in_sizes[1] / 2;
    const int C_ = in_sizes[21];
    const int D_ = in_sizes[23];
    const int Gn = (out_size - 1) / (C_ + D_);
    const int NB = (N + BSZ - 1) >> BSH;

    const int* src = ei;
    const int* dst = ei + E;

    size_t NH = (size_t)N * HF;
    char* p = (char*)d_ws;
    unsigned short* xb = (unsigned short*)p; p += NH * 2;
    unsigned short* U  = (unsigned short*)p; p += NH * 2;
    unsigned short* Hp = (unsigned short*)p; p += NH * 2;
    unsigned short* WtAll = (unsigned short*)p; p += 4 * 16384 * 2;
    float* S1    = (float*)p; p += HF * 4;
    float* S2    = (float*)p; p += HF * 4;
    float* scale = (float*)p; p += HF * 4;
    float* shift = (float*)p; p += HF * 4;
    float* z       = (float*)p; p += (size_t)Gn * HF * 4;
    float* partial = (float*)p; p += 1024 * 4;
    int* gstart = (int*)p; p += (Gn + 1) * 4;
    int* bcnt   = (int*)p; p += NBMAX * 4;
    int* boff   = (int*)p; p += (NBMAX + 1) * 4;
    int* bcur   = (int*)p; p += NBMAX * 4;
    int* off    = (int*)p; p += (N + 1) * 4;
    int* esrc   = (int*)p; p += E * 4;
    unsigned* ebuf = (unsigned*)p; p += E * 4;

    unsigned short* Wt1a = WtAll;
    unsigned short* Wt1b = WtAll + 16384;
    unsigned short* Wt2a = WtAll + 32768;
    unsigned short* Wt2b = WtAll + 49152;

    float* out1 = (float*)d_out;
    float* out3 = out1 + (size_t)Gn * C_;
    float* outm = out3 + (size_t)Gn * D_;

    int nBlocks   = (N + 255) / 256;
    int castBlk   = ((int)(NH / 8) + 255) / 256;
    int gatherBlk = (N * 16 + 255) / 256;
    int gemmBlk   = (N + 63) / 64;
    const int BINB = 512;
    int chunk = (E + BINB - 1) / BINB;
    const int P = 1024;
    float invN = 1.0f / (float)N;

    // ---- casts + CSR + bounds ----
    cast_x<<<castBlk, 256, 0, stream>>>(x, xb, (int)(NH / 8));
    cast_wt<<<4, 256, 0, stream>>>(W1a, W1b, W2a, W2b, WtAll);
    hipMemsetAsync(bcnt, 0, NB * sizeof(int), stream);
    bucket_hist<<<BINB, 256, 0, stream>>>(dst, bcnt, E, NB, chunk);
    bucket_scan<<<1, 256, 0, stream>>>(bcnt, boff, bcur, NB);
    bucket_bin<<<BINB, 256, 0, stream>>>(src, dst, bcur, ebuf, E, NB, chunk);
    bucket_fill<<<NB, 256, 0, stream>>>(ebuf, boff, off, esrc, N, NB, E);
    graph_bounds<<<nBlocks, 256, 0, stream>>>(batch, gstart, N, Gn);

    // ---- layer 1 (double-GEMM fused, BN stats in epilogue) ----
    gather_u<false><<<gatherBlk, 256, 0, stream>>>(xb, off, esrc, eps1, nullptr, nullptr, U, N);
    hipMemsetAsync(S1, 0, 2 * HF * sizeof(float), stream);
    gemm2_mfma<<<gemmBlk, 256, 0, stream>>>(U, Wt1a, b1a, Wt1b, b1b, Hp, S1, S2, N);
    bn_finalize<<<1, 128, 0, stream>>>(S1, S2, g1, be1, scale, shift, invN);

    // ---- layer 2 (BN1 folded into gather; BN2 folded into tail) ----
    gather_u<true><<<gatherBlk, 256, 0, stream>>>(Hp, off, esrc, eps2, scale, shift, U, N);
    hipMemsetAsync(S1, 0, 2 * HF * sizeof(float), stream);
    gemm2_mfma<<<gemmBlk, 256, 0, stream>>>(U, Wt2a, b2a, Wt2b, b2b, Hp, S1, S2, N);
    bn_finalize<<<1, 128, 0, stream>>>(S1, S2, g2, be2, scale, shift, invN);

    // ---- tail ----
    pool_lin1<<<Gn, 512, 0, stream>>>(Hp, scale, shift, gstart, Wlin1, blin1, z);
    mse_partial<<<P, 256, 0, stream>>>(Hp, scale, shift, Wloss, bloss, degree, partial, N);
    mse_final<<<1, 256, 0, stream>>>(partial, outm, invN, P);
    heads<<<Gn, 64, 0, stream>>>(z, Wlin2, blin2, Wlin4, blin4, out1, out3, C_, D_);
}